// Round 2
// baseline (1524.443 us; speedup 1.0000x reference)
//
#include <hip/hip_runtime.h>

// ============================================================================
// TransformerSubsetAggregator on MI355X (gfx950) — round 2
// Pipeline: k_prep (w->bf16) | k_sel(+LN1) | k_attnfused (QKV+attn+proj+res)
//           | k_ln2 | k_ff (FF1+gelu+FF2+res, barrier-free f-loop) | k_pool
//           | k_headmlp (out1+gelu+out2)
// Design: small LDS per block (<52KB) -> 3 blocks/CU = 12 waves/CU (vs 4).
// All GEMMs bf16 MFMA 16x16x32; fp32 LN/softmax/residual/accum.
// ws ~104MB: X fp32 64MB | H1/H2 bf16 32MB (aliased) | F | NPICK | weights.
// ============================================================================

#define DIM   256
#define LSEQ  128
#define KTOK  8

typedef __bf16 bf16x8 __attribute__((ext_vector_type(8)));
typedef float  f32x4  __attribute__((ext_vector_type(4)));

__device__ __forceinline__ f32x4 mfma16(bf16x8 a, bf16x8 b, f32x4 c) {
  // A/B frag: m(or n)=lane&15, k=(lane>>4)*8+j ; D: col=lane&15, row=(lane>>4)*4+reg
  return __builtin_amdgcn_mfma_f32_16x16x32_bf16(a, b, c, 0, 0, 0);
}

__device__ __forceinline__ unsigned short f2bf(float f) {
  unsigned u = __float_as_uint(f);
  u = (u + 0x7FFFu + ((u >> 16) & 1u)) >> 16;   // RNE
  return (unsigned short)u;
}

__device__ __forceinline__ float gelu_exact(float x) {
  return 0.5f * x * (1.f + erff(x * 0.70710678118654752f));
}

// ---------------------------------------------------------------------------
// k_prep: fp32 -> bf16 weights (w_out1 padded K 257 -> 320 with zeros)
// regions: wq 196608 | wo 65536 | wff1 262144 | wff2 262144 | wout1p 327680
//          | wout2 262144  => total 1376256
// ---------------------------------------------------------------------------
#define PREP_TOTAL 1376256
__global__ __launch_bounds__(256) void k_prep(
    const float* __restrict__ wqkv, const float* __restrict__ wo,
    const float* __restrict__ wff1, const float* __restrict__ wff2,
    const float* __restrict__ wout1, const float* __restrict__ wout2,
    unsigned short* __restrict__ oq, unsigned short* __restrict__ oo,
    unsigned short* __restrict__ of1, unsigned short* __restrict__ of2,
    unsigned short* __restrict__ oo1, unsigned short* __restrict__ oo2)
{
  int i = blockIdx.x * 256 + threadIdx.x;
  if (i < 196608) { oq[i] = f2bf(wqkv[i]); return; }
  i -= 196608;
  if (i < 65536)  { oo[i] = f2bf(wo[i]); return; }
  i -= 65536;
  if (i < 262144) { of1[i] = f2bf(wff1[i]); return; }
  i -= 262144;
  if (i < 262144) { of2[i] = f2bf(wff2[i]); return; }
  i -= 262144;
  if (i < 327680) {
    int r = i / 320, c = i - r * 320;
    oo1[i] = (c < 257) ? f2bf(wout1[r * 257 + c]) : (unsigned short)0;
    return;
  }
  i -= 327680;
  if (i < 262144) { oo2[i] = f2bf(wout2[i]); }
}

// ---------------------------------------------------------------------------
// k_sel: top-8 (exact lax.top_k ties: value desc, idx asc), sort picked idx
// ascending, gather v + pos_embed -> X fp32, fused LN1 -> H1 bf16.
// ---------------------------------------------------------------------------
__global__ __launch_bounds__(256) void k_sel(
    const float* __restrict__ v, const int* __restrict__ batch_idx,
    const int* __restrict__ mask, const float* __restrict__ rank_scores,
    const float* __restrict__ pos_embed,
    const float* __restrict__ ln1g, const float* __restrict__ ln1b,
    float* __restrict__ X, unsigned short* __restrict__ H1,
    int* __restrict__ NPICK)
{
  const int c = blockIdx.x;
  const int tid = threadIdx.x;
  __shared__ int s_mem[KTOK];
  __shared__ int s_np;

  if (tid < 64) {
    const int l = tid;
    unsigned long long key[2];
    #pragma unroll
    for (int t = 0; t < 2; ++t) {
      int p = l + 64 * t;
      int mk = mask[c * LSEQ + p];
      float s = rank_scores[c * LSEQ + p];
      unsigned u = __float_as_uint(s);
      u = (u & 0x80000000u) ? ~u : (u | 0x80000000u);
      unsigned long long kk =
          ((unsigned long long)u << 32) | (unsigned long long)(0xFFFFFFFFu - (unsigned)p);
      key[t] = mk ? kk : 0ull;
    }
    int w[KTOK];
    #pragma unroll
    for (int r = 0; r < KTOK; ++r) w[r] = 0x7FFFFFFF;
    int np = 0;
    for (int r = 0; r < KTOK; ++r) {
      unsigned long long best = key[0] > key[1] ? key[0] : key[1];
      for (int off = 32; off > 0; off >>= 1) {
        unsigned long long o = __shfl_xor(best, off, 64);
        if (o > best) best = o;
      }
      if (best == 0ull) break;
      int idx = (int)(0xFFFFFFFFu - (unsigned)(best & 0xFFFFFFFFull));
      w[np++] = idx;
      if (key[0] == best) key[0] = 0ull;
      if (key[1] == best) key[1] = 0ull;
    }
    #pragma unroll
    for (int a = 0; a < KTOK - 1; ++a)
      #pragma unroll
      for (int b2 = 0; b2 < KTOK - 1 - a; ++b2) {
        int x0 = w[b2], x1 = w[b2 + 1];
        w[b2] = min(x0, x1); w[b2 + 1] = max(x0, x1);
      }
    if (l < KTOK) s_mem[l] = (l < np) ? batch_idx[c * LSEQ + w[l]] : -1;
    if (l == 0) { s_np = np; NPICK[c] = np; }
  }
  __syncthreads();

  const int np = s_np;
  const int j = tid >> 5, q = tid & 31;     // 32 threads per token row
  const int r = s_mem[j];
  const float4* v4  = (const float4*)v;
  const float4* pe4 = (const float4*)pos_embed;
  float4* X4 = (float4*)X;

  float4 xv[2];
  #pragma unroll
  for (int rep = 0; rep < 2; ++rep) {
    int f = q + rep * 32;
    float4 pe = pe4[j * 64 + f];
    float4 val = make_float4(0.f, 0.f, 0.f, 0.f);
    if (j < np) val = v4[(long)r * 64 + f];
    xv[rep].x = val.x + pe.x; xv[rep].y = val.y + pe.y;
    xv[rep].z = val.z + pe.z; xv[rep].w = val.w + pe.w;
    X4[((long)c * KTOK + j) * 64 + f] = xv[rep];
  }
  // fused LN1 over the row (32 threads x 8 vals = 256)
  float sum = 0.f, ss = 0.f;
  #pragma unroll
  for (int rep = 0; rep < 2; ++rep) {
    sum += xv[rep].x + xv[rep].y + xv[rep].z + xv[rep].w;
    ss  += xv[rep].x * xv[rep].x + xv[rep].y * xv[rep].y
         + xv[rep].z * xv[rep].z + xv[rep].w * xv[rep].w;
  }
  #pragma unroll
  for (int off = 1; off <= 16; off <<= 1) {
    sum += __shfl_xor(sum, off); ss += __shfl_xor(ss, off);
  }
  const float mu = sum * (1.f / 256.f);
  const float var = ss * (1.f / 256.f) - mu * mu;
  const float rstd = rsqrtf(var + 1e-5f);
  #pragma unroll
  for (int rep = 0; rep < 2; ++rep) {
    const int col = (q + rep * 32) * 4;
    ushort4 h;
    h.x = f2bf((xv[rep].x - mu) * rstd * ln1g[col + 0] + ln1b[col + 0]);
    h.y = f2bf((xv[rep].y - mu) * rstd * ln1g[col + 1] + ln1b[col + 1]);
    h.z = f2bf((xv[rep].z - mu) * rstd * ln1g[col + 2] + ln1b[col + 2]);
    h.w = f2bf((xv[rep].w - mu) * rstd * ln1g[col + 3] + ln1b[col + 3]);
    *(ushort4*)&H1[((long)c * KTOK + j) * DIM + col] = h;
  }
}

// ---------------------------------------------------------------------------
// k_attnfused: 4 chains (32 tokens) per block. QKV GEMM (A-frags in regs from
// H1, B from global/L2) -> LDS QKV tile -> attention -> o-proj + residual.
// LDS 49.7KB -> 3 blocks/CU.
// ---------------------------------------------------------------------------
#define QKVP 776   // 768 + 8 (row stride 1552B = 388 dw === 4 mod 32: 2-way only)

__global__ __launch_bounds__(256, 3) void k_attnfused(
    const unsigned short* __restrict__ H1, float* __restrict__ X,
    const int* __restrict__ NPICK,
    const unsigned short* __restrict__ wq, const float* __restrict__ bqkv,
    const unsigned short* __restrict__ wo, const float* __restrict__ bo)
{
  __shared__ unsigned short sQKV[32 * QKVP];
  __shared__ int s_np[4];

  const int tid = threadIdx.x;
  const int blk = blockIdx.x;
  const long tokbase = (long)blk * 32;

  if (tid < 4) s_np[tid] = NPICK[blk * 4 + tid];

  const int wv = tid >> 6, ln = tid & 63;
  const int lr = ln & 15, lq = ln >> 4;
  const int mh = wv & 1, nh = wv >> 1;
  const int m0 = mh * 16;
  const f32x4 vzero = {0.f, 0.f, 0.f, 0.f};

  // ---- QKV GEMM: rows tokbase+m0..+15, cols nh*384..+383 ----
  bf16x8 af[8];
  {
    const unsigned short* arow = H1 + (tokbase + m0 + lr) * DIM + lq * 8;
    #pragma unroll
    for (int s = 0; s < 8; ++s) af[s] = *(const bf16x8*)&arow[s * 32];
  }
  for (int c6 = 0; c6 < 6; ++c6) {
    const int n0 = nh * 384 + c6 * 64;
    f32x4 acc[4];
    #pragma unroll
    for (int nt = 0; nt < 4; ++nt) acc[nt] = vzero;
    #pragma unroll
    for (int s = 0; s < 8; ++s) {
      #pragma unroll
      for (int nt = 0; nt < 4; ++nt) {
        bf16x8 b = *(const bf16x8*)&wq[(n0 + nt * 16 + lr) * 256 + s * 32 + lq * 8];
        acc[nt] = mfma16(af[s], b, acc[nt]);
      }
    }
    #pragma unroll
    for (int nt = 0; nt < 4; ++nt) {
      const int n = n0 + nt * 16 + lr;
      const float bias = bqkv[n];
      #pragma unroll
      for (int reg = 0; reg < 4; ++reg) {
        const int row = m0 + lq * 4 + reg;
        sQKV[row * QKVP + n] = f2bf(acc[nt][reg] + bias);
      }
    }
  }
  __syncthreads();

  // ---- attention: thread = (chain c 0..3, head hh 0..3, query qi 0..7) ----
  if (tid < 128) {
    const int c = tid >> 5, hh = (tid >> 3) & 3, qi = tid & 7;
    const int natt = max(1, s_np[c]);
    const int qrow = c * 8 + qi;
    float sc[8];
    #pragma unroll
    for (int j = 0; j < 8; ++j) sc[j] = -1e30f;
    for (int j = 0; j < natt; ++j) {
      float d = 0.f;
      #pragma unroll
      for (int dc = 0; dc < 8; ++dc) {
        bf16x8 qv = *(const bf16x8*)&sQKV[qrow * QKVP + hh * 64 + dc * 8];
        bf16x8 kv = *(const bf16x8*)&sQKV[(c * 8 + j) * QKVP + 256 + hh * 64 + dc * 8];
        #pragma unroll
        for (int e = 0; e < 8; ++e) d += (float)qv[e] * (float)kv[e];
      }
      sc[j] = d * 0.125f;
    }
    float mx = -1e30f;
    #pragma unroll
    for (int j = 0; j < 8; ++j) mx = fmaxf(mx, sc[j]);
    float pr[8]; float ssum = 0.f;
    #pragma unroll
    for (int j = 0; j < 8; ++j) {
      float e = (j < natt) ? __expf(sc[j] - mx) : 0.f;
      pr[j] = e; ssum += e;
    }
    const float inv = 1.f / ssum;
    #pragma unroll
    for (int dc = 0; dc < 8; ++dc) {
      float o8[8] = {0.f,0.f,0.f,0.f,0.f,0.f,0.f,0.f};
      for (int j = 0; j < natt; ++j) {
        const float pj = pr[j] * inv;
        bf16x8 vv = *(const bf16x8*)&sQKV[(c * 8 + j) * QKVP + 512 + hh * 64 + dc * 8];
        #pragma unroll
        for (int e = 0; e < 8; ++e) o8[e] += pj * (float)vv[e];
      }
      ushort4 h0, h1;
      h0.x = f2bf(o8[0]); h0.y = f2bf(o8[1]); h0.z = f2bf(o8[2]); h0.w = f2bf(o8[3]);
      h1.x = f2bf(o8[4]); h1.y = f2bf(o8[5]); h1.z = f2bf(o8[6]); h1.w = f2bf(o8[7]);
      *(ushort4*)&sQKV[qrow * QKVP + hh * 64 + dc * 8 + 0] = h0;   // own Q slice only
      *(ushort4*)&sQKV[qrow * QKVP + hh * 64 + dc * 8 + 4] = h1;
    }
  }
  __syncthreads();

  // ---- proj: wave = (m-tile mh, col-half nh): cols nh*128 + nt*16 ----
  {
    bf16x8 of[8];
    #pragma unroll
    for (int s = 0; s < 8; ++s)
      of[s] = *(const bf16x8*)&sQKV[(m0 + lr) * QKVP + s * 32 + lq * 8];
    f32x4 acc2[8];
    #pragma unroll
    for (int nt = 0; nt < 8; ++nt) acc2[nt] = vzero;
    #pragma unroll
    for (int s = 0; s < 8; ++s) {
      #pragma unroll
      for (int nt = 0; nt < 8; ++nt) {
        bf16x8 b = *(const bf16x8*)&wo[(nh * 128 + nt * 16 + lr) * 256 + s * 32 + lq * 8];
        acc2[nt] = mfma16(of[s], b, acc2[nt]);
      }
    }
    #pragma unroll
    for (int nt = 0; nt < 8; ++nt) {
      const int col = nh * 128 + nt * 16 + lr;
      const float bias = bo[col];
      #pragma unroll
      for (int reg = 0; reg < 4; ++reg) {
        const int row = m0 + lq * 4 + reg;
        const long gi = (tokbase + row) * DIM + col;
        X[gi] = X[gi] + acc2[nt][reg] + bias;
      }
    }
  }
}

// ---------------------------------------------------------------------------
// k_ln2: X fp32 -> H2 bf16 (64 rows/block, 4 threads/row)
// ---------------------------------------------------------------------------
__global__ __launch_bounds__(256) void k_ln2(
    const float* __restrict__ X, const float* __restrict__ g,
    const float* __restrict__ b, unsigned short* __restrict__ H2)
{
  const int tid = threadIdx.x;
  const long row = (long)blockIdx.x * 64 + (tid >> 2);
  const int p = tid & 3;
  const float4* xr = (const float4*)(X + row * DIM + p * 64);
  float4 xv[16];
  float sum = 0.f, ss = 0.f;
  #pragma unroll
  for (int i = 0; i < 16; ++i) {
    xv[i] = xr[i];
    sum += xv[i].x + xv[i].y + xv[i].z + xv[i].w;
    ss  += xv[i].x * xv[i].x + xv[i].y * xv[i].y + xv[i].z * xv[i].z + xv[i].w * xv[i].w;
  }
  sum += __shfl_xor(sum, 1); ss += __shfl_xor(ss, 1);
  sum += __shfl_xor(sum, 2); ss += __shfl_xor(ss, 2);
  const float mu = sum * (1.f / 256.f);
  const float var = ss * (1.f / 256.f) - mu * mu;
  const float rstd = rsqrtf(var + 1e-5f);
  #pragma unroll
  for (int i = 0; i < 16; ++i) {
    const int col = p * 64 + i * 4;
    ushort4 h;
    h.x = f2bf((xv[i].x - mu) * rstd * g[col + 0] + b[col + 0]);
    h.y = f2bf((xv[i].y - mu) * rstd * g[col + 1] + b[col + 1]);
    h.z = f2bf((xv[i].z - mu) * rstd * g[col + 2] + b[col + 2]);
    h.w = f2bf((xv[i].w - mu) * rstd * g[col + 3] + b[col + 3]);
    *(ushort4*)&H2[row * DIM + col] = h;
  }
}

// ---------------------------------------------------------------------------
// k_ff: x += gelu(h2@wff1^T+b1)@wff2^T+b2. 64 tokens/block, wave = m-tile.
// sG is wave-private -> NO barriers in the f-loop. LDS 42KB -> 3 blocks/CU.
// ---------------------------------------------------------------------------
#define SAP   264   // 256+8
#define SGPAD 72    // 64+8

__global__ __launch_bounds__(256, 3) void k_ff(
    float* __restrict__ X, const unsigned short* __restrict__ H2,
    const unsigned short* __restrict__ wff1, const unsigned short* __restrict__ wff2,
    const float* __restrict__ bff1, const float* __restrict__ bff2)
{
  __shared__ unsigned short sA[64 * SAP];
  __shared__ unsigned short sG[64 * SGPAD];
  const int tid = threadIdx.x;
  const long tokbase = (long)blockIdx.x * 64;

  for (int i = tid; i < 2048; i += 256) {       // stage H2 tile (64 x 256)
    const int r = i >> 5, cc = i & 31;
    *(float4*)&sA[r * SAP + cc * 8] = *(const float4*)&H2[(tokbase + r) * DIM + cc * 8];
  }
  __syncthreads();

  const int wv = tid >> 6, ln = tid & 63;
  const int lr = ln & 15, lq = ln >> 4;
  const int m0 = wv * 16;
  const f32x4 vzero = {0.f, 0.f, 0.f, 0.f};

  bf16x8 af[8];
  #pragma unroll
  for (int s = 0; s < 8; ++s)
    af[s] = *(const bf16x8*)&sA[(m0 + lr) * SAP + s * 32 + lq * 8];

  f32x4 acc3[16];
  #pragma unroll
  for (int nt = 0; nt < 16; ++nt) acc3[nt] = vzero;

  for (int f = 0; f < 16; ++f) {
    f32x4 ga[4];
    #pragma unroll
    for (int nt = 0; nt < 4; ++nt) ga[nt] = vzero;
    #pragma unroll
    for (int s = 0; s < 8; ++s) {
      #pragma unroll
      for (int nt = 0; nt < 4; ++nt) {
        bf16x8 b = *(const bf16x8*)&wff1[(f * 64 + nt * 16 + lr) * 256 + s * 32 + lq * 8];
        ga[nt] = mfma16(af[s], b, ga[nt]);
      }
    }
    #pragma unroll
    for (int nt = 0; nt < 4; ++nt) {
      const int n = f * 64 + nt * 16 + lr;
      const float bias = bff1[n];
      #pragma unroll
      for (int reg = 0; reg < 4; ++reg) {
        sG[(m0 + lq * 4 + reg) * SGPAD + nt * 16 + lr] = f2bf(gelu_exact(ga[nt][reg] + bias));
      }
    }
    // sG rows m0..m0+15 are written and read only by this wave: no barrier.
    #pragma unroll
    for (int s2 = 0; s2 < 2; ++s2) {
      bf16x8 ag = *(const bf16x8*)&sG[(m0 + lr) * SGPAD + s2 * 32 + lq * 8];
      #pragma unroll
      for (int nt = 0; nt < 16; ++nt) {
        bf16x8 b = *(const bf16x8*)&wff2[(nt * 16 + lr) * 1024 + f * 64 + s2 * 32 + lq * 8];
        acc3[nt] = mfma16(ag, b, acc3[nt]);
      }
    }
  }
  #pragma unroll
  for (int nt = 0; nt < 16; ++nt) {
    const int col = nt * 16 + lr;
    const float bias = bff2[col];
    #pragma unroll
    for (int reg = 0; reg < 4; ++reg) {
      const int row = m0 + lq * 4 + reg;
      const long gi = (tokbase + row) * DIM + col;
      X[gi] = X[gi] + acc3[nt][reg] + bias;
    }
  }
}

// ---------------------------------------------------------------------------
// k_pool: masked mean pool + log1p(count) -> F bf16 [8192, 320] (zero-padded)
// ---------------------------------------------------------------------------
__global__ __launch_bounds__(256) void k_pool(
    const float* __restrict__ X, const int* __restrict__ NPICK,
    const float* __restrict__ count, unsigned short* __restrict__ F)
{
  const int tid = threadIdx.x;
  const int cc = tid >> 2, p = tid & 3;
  const int chain = blockIdx.x * 64 + cc;
  const int np = NPICK[chain];
  const float inv = (np > 0) ? (1.f / (float)np) : 0.f;
  const float4* xb = (const float4*)(X + (long)chain * KTOK * DIM + p * 64);
  #pragma unroll
  for (int i = 0; i < 16; ++i) {
    float4 s = make_float4(0.f, 0.f, 0.f, 0.f);
    for (int j = 0; j < np; ++j) {
      float4 t = xb[j * 64 + i];
      s.x += t.x; s.y += t.y; s.z += t.z; s.w += t.w;
    }
    ushort4 h;
    h.x = f2bf(s.x * inv); h.y = f2bf(s.y * inv);
    h.z = f2bf(s.z * inv); h.w = f2bf(s.w * inv);
    *(ushort4*)&F[(long)chain * 320 + p * 64 + i * 4] = h;
  }
  if (p == 3) {
    F[(long)chain * 320 + 256] = f2bf(log1pf(count[chain]));
    for (int col = 257; col < 320; ++col) F[(long)chain * 320 + col] = 0;
  }
}

// ---------------------------------------------------------------------------
// k_headmlp: out = gelu(F@wout1p^T+b1)@wout2^T+b2. 64 chains/block.
// ---------------------------------------------------------------------------
#define SFP 328   // 320+8

__global__ __launch_bounds__(256, 3) void k_headmlp(
    const unsigned short* __restrict__ F,
    const unsigned short* __restrict__ wout1p, const unsigned short* __restrict__ wout2,
    const float* __restrict__ bout1, const float* __restrict__ bout2,
    float* __restrict__ out)
{
  __shared__ unsigned short sF[64 * SFP];
  __shared__ unsigned short sG[64 * SGPAD];
  const int tid = threadIdx.x;
  const long rowbase = (long)blockIdx.x * 64;

  for (int i = tid; i < 2560; i += 256) {       // stage F tile (64 x 320)
    const int r = i / 40, cc = i - r * 40;
    *(float4*)&sF[r * SFP + cc * 8] = *(const float4*)&F[(rowbase + r) * 320 + cc * 8];
  }
  __syncthreads();

  const int wv = tid >> 6, ln = tid & 63;
  const int lr = ln & 15, lq = ln >> 4;
  const int m0 = wv * 16;
  const f32x4 vzero = {0.f, 0.f, 0.f, 0.f};

  f32x4 oacc[16];
  #pragma unroll
  for (int nt = 0; nt < 16; ++nt) oacc[nt] = vzero;

  for (int f = 0; f < 16; ++f) {
    f32x4 ga[4];
    #pragma unroll
    for (int nt = 0; nt < 4; ++nt) ga[nt] = vzero;
    #pragma unroll
    for (int s = 0; s < 10; ++s) {              // K = 320
      bf16x8 a = *(const bf16x8*)&sF[(m0 + lr) * SFP + s * 32 + lq * 8];
      #pragma unroll
      for (int nt = 0; nt < 4; ++nt) {
        bf16x8 b = *(const bf16x8*)&wout1p[(f * 64 + nt * 16 + lr) * 320 + s * 32 + lq * 8];
        ga[nt] = mfma16(a, b, ga[nt]);
      }
    }
    #pragma unroll
    for (int nt = 0; nt < 4; ++nt) {
      const int n = f * 64 + nt * 16 + lr;
      const float bias = bout1[n];
      #pragma unroll
      for (int reg = 0; reg < 4; ++reg) {
        sG[(m0 + lq * 4 + reg) * SGPAD + nt * 16 + lr] = f2bf(gelu_exact(ga[nt][reg] + bias));
      }
    }
    // wave-private sG: no barrier
    #pragma unroll
    for (int s2 = 0; s2 < 2; ++s2) {
      bf16x8 ag = *(const bf16x8*)&sG[(m0 + lr) * SGPAD + s2 * 32 + lq * 8];
      #pragma unroll
      for (int nt = 0; nt < 16; ++nt) {
        bf16x8 b = *(const bf16x8*)&wout2[(nt * 16 + lr) * 1024 + f * 64 + s2 * 32 + lq * 8];
        oacc[nt] = mfma16(ag, b, oacc[nt]);
      }
    }
  }
  #pragma unroll
  for (int nt = 0; nt < 16; ++nt) {
    const int col = nt * 16 + lr;
    const float bias = bout2[col];
    #pragma unroll
    for (int reg = 0; reg < 4; ++reg) {
      const int row = m0 + lq * 4 + reg;
      out[(rowbase + row) * DIM + col] = oacc[nt][reg] + bias;
    }
  }
}

// ---------------------------------------------------------------------------
extern "C" void kernel_launch(void* const* d_in, const int* in_sizes, int n_in,
                              void* d_out, int out_size, void* d_ws, size_t ws_size,
                              hipStream_t stream) {
  (void)in_sizes; (void)n_in; (void)out_size; (void)ws_size;
  const float* v          = (const float*)d_in[0];
  const int*   batch_idx  = (const int*)  d_in[1];
  const int*   mask       = (const int*)  d_in[2];
  const float* count      = (const float*)d_in[3];
  const float* rank       = (const float*)d_in[4];
  const float* pe         = (const float*)d_in[5];
  const float* w_qkv      = (const float*)d_in[6];
  const float* b_qkv      = (const float*)d_in[7];
  const float* w_o        = (const float*)d_in[8];
  const float* b_o        = (const float*)d_in[9];
  const float* ln1g       = (const float*)d_in[10];
  const float* ln1b       = (const float*)d_in[11];
  const float* ln2g       = (const float*)d_in[12];
  const float* ln2b       = (const float*)d_in[13];
  const float* w_ff1      = (const float*)d_in[14];
  const float* b_ff1      = (const float*)d_in[15];
  const float* w_ff2      = (const float*)d_in[16];
  const float* b_ff2      = (const float*)d_in[17];
  const float* w_out1     = (const float*)d_in[18];
  const float* b_out1     = (const float*)d_in[19];
  const float* w_out2     = (const float*)d_in[20];
  const float* b_out2     = (const float*)d_in[21];
  float* out = (float*)d_out;

  char* ws = (char*)d_ws;
  float*          X     = (float*)ws;                              // 67,108,864
  unsigned short* H1    = (unsigned short*)(ws + 67108864);        // 33,554,432 (H2 aliases H1)
  unsigned short* H2    = H1;                                      // H1 dead after k_attnfused
  unsigned short* F     = (unsigned short*)(ws + 100663296);       //  5,242,880
  int*            NPICK = (int*)(ws + 105906176);                  //     32,768
  unsigned short* wq_bf   = (unsigned short*)(ws + 105938944);     //    393,216
  unsigned short* wo_bf   = (unsigned short*)(ws + 106332160);     //    131,072
  unsigned short* wff1_bf = (unsigned short*)(ws + 106463232);     //    524,288
  unsigned short* wff2_bf = (unsigned short*)(ws + 106987520);     //    524,288
  unsigned short* wo1_bf  = (unsigned short*)(ws + 107511808);     //    655,360 (1024x320 padded)
  unsigned short* wo2_bf  = (unsigned short*)(ws + 108167168);     //    524,288 -> end 108,691,456

  k_prep<<<(PREP_TOTAL + 255) / 256, 256, 0, stream>>>(
      w_qkv, w_o, w_ff1, w_ff2, w_out1, w_out2,
      wq_bf, wo_bf, wff1_bf, wff2_bf, wo1_bf, wo2_bf);

  k_sel<<<8192, 256, 0, stream>>>(v, batch_idx, mask, rank, pe,
                                  ln1g, ln1b, X, H1, NPICK);

  k_attnfused<<<2048, 256, 0, stream>>>(H1, X, NPICK, wq_bf, b_qkv, wo_bf, b_o);

  k_ln2<<<1024, 256, 0, stream>>>(X, ln2g, ln2b, H2);

  k_ff<<<1024, 256, 0, stream>>>(X, H2, wff1_bf, wff2_bf, b_ff1, b_ff2);

  k_pool<<<128, 256, 0, stream>>>(X, NPICK, count, F);

  k_headmlp<<<128, 256, 0, stream>>>(F, wo1_bf, wo2_bf, b_out1, b_out2, out);
}

// Round 3
// 1170.127 us; speedup vs baseline: 1.3028x; 1.3028x over previous
//
#include <hip/hip_runtime.h>

// ============================================================================
// TransformerSubsetAggregator on MI355X (gfx950) — round 3
// Key change vs r2: ALL MFMA operands are pre-packed into fragment-major
// layout (group ((ntile*KC+s)*64+lane)*8) so every A/B load is a fully
// coalesced 16B/lane stream. r2's B-from-global-in-fragment-layout was a
// 16-way split gather -> request-pipe bound (MfmaUtil 3.9%).
// Pipeline: k_prep(pack w) | k_sel(topk+gather+LN1->H1p) | k_attnfused |
//           k_ln2(->H2p) | k_ff | k_pool(->Fp) | k_headmlp
// ============================================================================

#define DIM   256
#define LSEQ  128
#define KTOK  8

typedef __bf16 bf16x8 __attribute__((ext_vector_type(8)));
typedef float  f32x4  __attribute__((ext_vector_type(4)));
typedef unsigned short u16x8 __attribute__((ext_vector_type(8)));

__device__ __forceinline__ f32x4 mfma16(bf16x8 a, bf16x8 b, f32x4 c) {
  // A/B frag: m(or n)=lane&15, k=(lane>>4)*8+j ; D: col=lane&15, row=(lane>>4)*4+reg
  return __builtin_amdgcn_mfma_f32_16x16x32_bf16(a, b, c, 0, 0, 0);
}

__device__ __forceinline__ unsigned short f2bf(float f) {
  unsigned u = __float_as_uint(f);
  u = (u + 0x7FFFu + ((u >> 16) & 1u)) >> 16;   // RNE
  return (unsigned short)u;
}

__device__ __forceinline__ float gelu_exact(float x) {
  return 0.5f * x * (1.f + erff(x * 0.70710678118654752f));
}

// ---------------------------------------------------------------------------
// k_prep: pack weights fp32 -> bf16 fragment-major.
// For W[N][K]: dst group g=((ntile*KC+s)*64+ln) holds 8 bf16:
//   W[ntile*16+(ln&15)][s*32+(ln>>4)*8 + j], j=0..7  (zero beyond Klim).
// ---------------------------------------------------------------------------
__device__ __forceinline__ void pack_region(
    const float* __restrict__ src, unsigned short* __restrict__ dst,
    int g, int KC, int Ksrc, int Klim)
{
  const int ln = g & 63;
  const int t = g >> 6;
  const int s = t % KC;
  const int ntile = t / KC;
  const int row = ntile * 16 + (ln & 15);
  const int c0 = s * 32 + (ln >> 4) * 8;
  u16x8 o;
  #pragma unroll
  for (int j = 0; j < 8; ++j) {
    float val = (c0 + j < Klim) ? src[(long)row * Ksrc + c0 + j] : 0.f;
    o[j] = f2bf(val);
  }
  *(u16x8*)&dst[(long)g * 8] = o;
}

#define PREP_GROUPS 172032   // 24576+8192+32768+32768+40960+32768
__global__ __launch_bounds__(256) void k_prep(
    const float* __restrict__ wqkv, const float* __restrict__ wo,
    const float* __restrict__ wff1, const float* __restrict__ wff2,
    const float* __restrict__ wout1, const float* __restrict__ wout2,
    unsigned short* __restrict__ oq, unsigned short* __restrict__ oo,
    unsigned short* __restrict__ of1, unsigned short* __restrict__ of2,
    unsigned short* __restrict__ oo1, unsigned short* __restrict__ oo2)
{
  int g = blockIdx.x * 256 + threadIdx.x;
  if (g < 24576) { pack_region(wqkv, oq, g, 8, 256, 256); return; }
  g -= 24576;
  if (g < 8192)  { pack_region(wo, oo, g, 8, 256, 256); return; }
  g -= 8192;
  if (g < 32768) { pack_region(wff1, of1, g, 8, 256, 256); return; }
  g -= 32768;
  if (g < 32768) { pack_region(wff2, of2, g, 32, 1024, 1024); return; }
  g -= 32768;
  if (g < 40960) { pack_region(wout1, oo1, g, 10, 257, 257); return; }
  g -= 40960;
  if (g < 32768) { pack_region(wout2, oo2, g, 32, 1024, 1024); }
}

// ---------------------------------------------------------------------------
// k_sel: top-8 (lax.top_k ties: value desc, idx asc), sort picked idx asc,
// gather v + pos_embed -> X fp32 (row-major), fused LN1 -> H1 PACKED bf16.
// ---------------------------------------------------------------------------
__global__ __launch_bounds__(256) void k_sel(
    const float* __restrict__ v, const int* __restrict__ batch_idx,
    const int* __restrict__ mask, const float* __restrict__ rank_scores,
    const float* __restrict__ pos_embed,
    const float* __restrict__ ln1g, const float* __restrict__ ln1b,
    float* __restrict__ X, unsigned short* __restrict__ H1p,
    int* __restrict__ NPICK)
{
  const int c = blockIdx.x;
  const int tid = threadIdx.x;
  __shared__ int s_mem[KTOK];
  __shared__ int s_np;

  if (tid < 64) {
    const int l = tid;
    unsigned long long key[2];
    #pragma unroll
    for (int t = 0; t < 2; ++t) {
      int p = l + 64 * t;
      int mk = mask[c * LSEQ + p];
      float s = rank_scores[c * LSEQ + p];
      unsigned u = __float_as_uint(s);
      u = (u & 0x80000000u) ? ~u : (u | 0x80000000u);
      unsigned long long kk =
          ((unsigned long long)u << 32) | (unsigned long long)(0xFFFFFFFFu - (unsigned)p);
      key[t] = mk ? kk : 0ull;
    }
    int w[KTOK];
    #pragma unroll
    for (int r = 0; r < KTOK; ++r) w[r] = 0x7FFFFFFF;
    int np = 0;
    for (int r = 0; r < KTOK; ++r) {
      unsigned long long best = key[0] > key[1] ? key[0] : key[1];
      for (int off = 32; off > 0; off >>= 1) {
        unsigned long long o = __shfl_xor(best, off, 64);
        if (o > best) best = o;
      }
      if (best == 0ull) break;
      int idx = (int)(0xFFFFFFFFu - (unsigned)(best & 0xFFFFFFFFull));
      w[np++] = idx;
      if (key[0] == best) key[0] = 0ull;
      if (key[1] == best) key[1] = 0ull;
    }
    #pragma unroll
    for (int a = 0; a < KTOK - 1; ++a)
      #pragma unroll
      for (int b2 = 0; b2 < KTOK - 1 - a; ++b2) {
        int x0 = w[b2], x1 = w[b2 + 1];
        w[b2] = min(x0, x1); w[b2 + 1] = max(x0, x1);
      }
    if (l < KTOK) s_mem[l] = (l < np) ? batch_idx[c * LSEQ + w[l]] : -1;
    if (l == 0) { s_np = np; NPICK[c] = np; }
  }
  __syncthreads();

  const int np = s_np;
  const int j = tid >> 5, q = tid & 31;     // 32 threads/token, 8 cols each
  const int r = s_mem[j];
  const float4* v4  = (const float4*)v;
  const float4* pe4 = (const float4*)pos_embed;
  float4* X4 = (float4*)X;

  float4 xv[2];                              // cols q*8 .. q*8+7
  #pragma unroll
  for (int rep = 0; rep < 2; ++rep) {
    const int f = 2 * q + rep;
    float4 pe = pe4[j * 64 + f];
    float4 val = make_float4(0.f, 0.f, 0.f, 0.f);
    if (j < np) val = v4[(long)r * 64 + f];
    xv[rep].x = val.x + pe.x; xv[rep].y = val.y + pe.y;
    xv[rep].z = val.z + pe.z; xv[rep].w = val.w + pe.w;
    X4[((long)c * KTOK + j) * 64 + f] = xv[rep];
  }
  float sum = 0.f, ss = 0.f;
  #pragma unroll
  for (int rep = 0; rep < 2; ++rep) {
    sum += xv[rep].x + xv[rep].y + xv[rep].z + xv[rep].w;
    ss  += xv[rep].x * xv[rep].x + xv[rep].y * xv[rep].y
         + xv[rep].z * xv[rep].z + xv[rep].w * xv[rep].w;
  }
  #pragma unroll
  for (int off = 1; off <= 16; off <<= 1) {
    sum += __shfl_xor(sum, off); ss += __shfl_xor(ss, off);
  }
  const float mu = sum * (1.f / 256.f);
  const float var = ss * (1.f / 256.f) - mu * mu;
  const float rstd = rsqrtf(var + 1e-5f);
  // packed H1 write: token t -> (mtile=t>>4, lr=t&15); col group q -> (s=q>>2, lq=q&3)
  const int t = c * KTOK + j;
  const int mtile = t >> 4, lr = t & 15;
  const int s = q >> 2, lq = q & 3;
  u16x8 o;
  const int col = q * 8;
  o[0] = f2bf((xv[0].x - mu) * rstd * ln1g[col + 0] + ln1b[col + 0]);
  o[1] = f2bf((xv[0].y - mu) * rstd * ln1g[col + 1] + ln1b[col + 1]);
  o[2] = f2bf((xv[0].z - mu) * rstd * ln1g[col + 2] + ln1b[col + 2]);
  o[3] = f2bf((xv[0].w - mu) * rstd * ln1g[col + 3] + ln1b[col + 3]);
  o[4] = f2bf((xv[1].x - mu) * rstd * ln1g[col + 4] + ln1b[col + 4]);
  o[5] = f2bf((xv[1].y - mu) * rstd * ln1g[col + 5] + ln1b[col + 5]);
  o[6] = f2bf((xv[1].z - mu) * rstd * ln1g[col + 6] + ln1b[col + 6]);
  o[7] = f2bf((xv[1].w - mu) * rstd * ln1g[col + 7] + ln1b[col + 7]);
  *(u16x8*)&H1p[((long)(mtile * 8 + s) * 64 + lq * 16 + lr) * 8] = o;
}

// ---------------------------------------------------------------------------
// k_attnfused: 4 chains (32 tokens)/block. QKV GEMM (A from packed H1, B from
// packed wq — all coalesced) -> LDS QKV tile -> attention -> o-proj + residual.
// ---------------------------------------------------------------------------
#define QKVP 776   // 768+8 shorts

__global__ __launch_bounds__(256, 3) void k_attnfused(
    const unsigned short* __restrict__ H1p, float* __restrict__ X,
    const int* __restrict__ NPICK,
    const unsigned short* __restrict__ wqp, const float* __restrict__ bqkv,
    const unsigned short* __restrict__ wop, const float* __restrict__ bo)
{
  __shared__ unsigned short sQKV[32 * QKVP];
  __shared__ int s_np[4];

  const int tid = threadIdx.x;
  const int blk = blockIdx.x;
  const long tokbase = (long)blk * 32;

  if (tid < 4) s_np[tid] = NPICK[blk * 4 + tid];

  const int wv = tid >> 6, ln = tid & 63;
  const int lr = ln & 15, lq = ln >> 4;
  const int mh = wv & 1, nh = wv >> 1;
  const int m0 = mh * 16;
  const int mtile = blk * 2 + mh;
  const f32x4 vzero = {0.f, 0.f, 0.f, 0.f};

  bf16x8 af[8];
  #pragma unroll
  for (int s = 0; s < 8; ++s)
    af[s] = *(const bf16x8*)&H1p[((long)(mtile * 8 + s) * 64 + ln) * 8];

  // ---- QKV GEMM: cols nh*384 .. +383 ----
  for (int c6 = 0; c6 < 6; ++c6) {
    f32x4 acc[4];
    #pragma unroll
    for (int nt = 0; nt < 4; ++nt) acc[nt] = vzero;
    #pragma unroll
    for (int s = 0; s < 8; ++s) {
      #pragma unroll
      for (int nt = 0; nt < 4; ++nt) {
        const int ntile = nh * 24 + c6 * 4 + nt;
        bf16x8 b = *(const bf16x8*)&wqp[((long)(ntile * 8 + s) * 64 + ln) * 8];
        acc[nt] = mfma16(af[s], b, acc[nt]);
      }
    }
    #pragma unroll
    for (int nt = 0; nt < 4; ++nt) {
      const int n = nh * 384 + c6 * 64 + nt * 16 + lr;
      const float bias = bqkv[n];
      #pragma unroll
      for (int reg = 0; reg < 4; ++reg) {
        const int row = m0 + lq * 4 + reg;
        sQKV[row * QKVP + n] = f2bf(acc[nt][reg] + bias);
      }
    }
  }
  __syncthreads();

  // ---- attention: thread = (chain c 0..3, head hh 0..3, query qi 0..7) ----
  if (tid < 128) {
    const int c = tid >> 5, hh = (tid >> 3) & 3, qi = tid & 7;
    const int natt = max(1, s_np[c]);
    const int qrow = c * 8 + qi;
    float sc[8];
    #pragma unroll
    for (int j = 0; j < 8; ++j) sc[j] = -1e30f;
    for (int j = 0; j < natt; ++j) {
      float d = 0.f;
      #pragma unroll
      for (int dc = 0; dc < 8; ++dc) {
        bf16x8 qv = *(const bf16x8*)&sQKV[qrow * QKVP + hh * 64 + dc * 8];
        bf16x8 kv = *(const bf16x8*)&sQKV[(c * 8 + j) * QKVP + 256 + hh * 64 + dc * 8];
        #pragma unroll
        for (int e = 0; e < 8; ++e) d += (float)qv[e] * (float)kv[e];
      }
      sc[j] = d * 0.125f;
    }
    float mx = -1e30f;
    #pragma unroll
    for (int j = 0; j < 8; ++j) mx = fmaxf(mx, sc[j]);
    float pr[8]; float ssum = 0.f;
    #pragma unroll
    for (int j = 0; j < 8; ++j) {
      float e = (j < natt) ? __expf(sc[j] - mx) : 0.f;
      pr[j] = e; ssum += e;
    }
    const float inv = 1.f / ssum;
    #pragma unroll
    for (int dc = 0; dc < 8; ++dc) {
      float o8[8] = {0.f,0.f,0.f,0.f,0.f,0.f,0.f,0.f};
      for (int j = 0; j < natt; ++j) {
        const float pj = pr[j] * inv;
        bf16x8 vv = *(const bf16x8*)&sQKV[(c * 8 + j) * QKVP + 512 + hh * 64 + dc * 8];
        #pragma unroll
        for (int e = 0; e < 8; ++e) o8[e] += pj * (float)vv[e];
      }
      ushort4 h0, h1;
      h0.x = f2bf(o8[0]); h0.y = f2bf(o8[1]); h0.z = f2bf(o8[2]); h0.w = f2bf(o8[3]);
      h1.x = f2bf(o8[4]); h1.y = f2bf(o8[5]); h1.z = f2bf(o8[6]); h1.w = f2bf(o8[7]);
      *(ushort4*)&sQKV[qrow * QKVP + hh * 64 + dc * 8 + 0] = h0;   // own Q slice
      *(ushort4*)&sQKV[qrow * QKVP + hh * 64 + dc * 8 + 4] = h1;
    }
  }
  __syncthreads();

  // ---- proj: A=o from LDS, B from packed wo; cols nh*128 + nt*16 ----
  {
    bf16x8 of[8];
    #pragma unroll
    for (int s = 0; s < 8; ++s)
      of[s] = *(const bf16x8*)&sQKV[(m0 + lr) * QKVP + s * 32 + lq * 8];
    f32x4 acc2[8];
    #pragma unroll
    for (int nt = 0; nt < 8; ++nt) acc2[nt] = vzero;
    #pragma unroll
    for (int s = 0; s < 8; ++s) {
      #pragma unroll
      for (int nt = 0; nt < 8; ++nt) {
        const int ntile = nh * 8 + nt;
        bf16x8 b = *(const bf16x8*)&wop[((long)(ntile * 8 + s) * 64 + ln) * 8];
        acc2[nt] = mfma16(of[s], b, acc2[nt]);
      }
    }
    #pragma unroll
    for (int nt = 0; nt < 8; ++nt) {
      const int col = nh * 128 + nt * 16 + lr;
      const float bias = bo[col];
      #pragma unroll
      for (int reg = 0; reg < 4; ++reg) {
        const int row = m0 + lq * 4 + reg;
        const long gi = (tokbase + row) * DIM + col;
        X[gi] = X[gi] + acc2[nt][reg] + bias;
      }
    }
  }
}

// ---------------------------------------------------------------------------
// k_ln2: X fp32 -> H2 PACKED bf16 (64 rows/block, 4 threads/row)
// ---------------------------------------------------------------------------
__global__ __launch_bounds__(256) void k_ln2(
    const float* __restrict__ X, const float* __restrict__ g,
    const float* __restrict__ b, unsigned short* __restrict__ H2p)
{
  const int tid = threadIdx.x;
  const int row = blockIdx.x * 64 + (tid >> 2);
  const int p = tid & 3;
  const float4* xr = (const float4*)(X + (long)row * DIM + p * 64);
  float4 xv[16];
  float sum = 0.f, ss = 0.f;
  #pragma unroll
  for (int i = 0; i < 16; ++i) {
    xv[i] = xr[i];
    sum += xv[i].x + xv[i].y + xv[i].z + xv[i].w;
    ss  += xv[i].x * xv[i].x + xv[i].y * xv[i].y + xv[i].z * xv[i].z + xv[i].w * xv[i].w;
  }
  sum += __shfl_xor(sum, 1); ss += __shfl_xor(ss, 1);
  sum += __shfl_xor(sum, 2); ss += __shfl_xor(ss, 2);
  const float mu = sum * (1.f / 256.f);
  const float var = ss * (1.f / 256.f) - mu * mu;
  const float rstd = rsqrtf(var + 1e-5f);
  const int mtile = row >> 4, lr = row & 15;
  #pragma unroll
  for (int i = 0; i < 16; i += 2) {
    const int q = p * 8 + (i >> 1);
    const int s = q >> 2, lq = q & 3;
    const int col = q * 8;
    u16x8 o;
    o[0] = f2bf((xv[i].x - mu) * rstd * g[col + 0] + b[col + 0]);
    o[1] = f2bf((xv[i].y - mu) * rstd * g[col + 1] + b[col + 1]);
    o[2] = f2bf((xv[i].z - mu) * rstd * g[col + 2] + b[col + 2]);
    o[3] = f2bf((xv[i].w - mu) * rstd * g[col + 3] + b[col + 3]);
    o[4] = f2bf((xv[i+1].x - mu) * rstd * g[col + 4] + b[col + 4]);
    o[5] = f2bf((xv[i+1].y - mu) * rstd * g[col + 5] + b[col + 5]);
    o[6] = f2bf((xv[i+1].z - mu) * rstd * g[col + 6] + b[col + 6]);
    o[7] = f2bf((xv[i+1].w - mu) * rstd * g[col + 7] + b[col + 7]);
    *(u16x8*)&H2p[((long)(mtile * 8 + s) * 64 + lq * 16 + lr) * 8] = o;
  }
}

// ---------------------------------------------------------------------------
// k_ff: x += gelu(h2@wff1^T+b1)@wff2^T+b2. 64 tokens/block, wave = m-tile.
// A/B fully coalesced from packed buffers; only sG (wave-private) in LDS,
// NO barriers anywhere.
// ---------------------------------------------------------------------------
#define SGPAD 72    // 64+8

__global__ __launch_bounds__(256, 3) void k_ff(
    float* __restrict__ X, const unsigned short* __restrict__ H2p,
    const unsigned short* __restrict__ w1p, const unsigned short* __restrict__ w2p,
    const float* __restrict__ bff1, const float* __restrict__ bff2)
{
  __shared__ unsigned short sG[64 * SGPAD];
  const int tid = threadIdx.x;
  const int wv = tid >> 6, ln = tid & 63;
  const int lr = ln & 15, lq = ln >> 4;
  const int m0 = wv * 16;
  const int mtile = blockIdx.x * 4 + wv;
  const long tokbase = (long)blockIdx.x * 64;
  const f32x4 vzero = {0.f, 0.f, 0.f, 0.f};

  bf16x8 af[8];
  #pragma unroll
  for (int s = 0; s < 8; ++s)
    af[s] = *(const bf16x8*)&H2p[((long)(mtile * 8 + s) * 64 + ln) * 8];

  f32x4 acc3[16];
  #pragma unroll
  for (int nt = 0; nt < 16; ++nt) acc3[nt] = vzero;

  for (int f = 0; f < 16; ++f) {
    f32x4 ga[4];
    #pragma unroll
    for (int nt = 0; nt < 4; ++nt) ga[nt] = vzero;
    #pragma unroll
    for (int s = 0; s < 8; ++s) {
      #pragma unroll
      for (int nt = 0; nt < 4; ++nt) {
        bf16x8 b = *(const bf16x8*)&w1p[((long)((f * 4 + nt) * 8 + s) * 64 + ln) * 8];
        ga[nt] = mfma16(af[s], b, ga[nt]);
      }
    }
    #pragma unroll
    for (int nt = 0; nt < 4; ++nt) {
      const int n = f * 64 + nt * 16 + lr;
      const float bias = bff1[n];
      #pragma unroll
      for (int reg = 0; reg < 4; ++reg) {
        sG[(m0 + lq * 4 + reg) * SGPAD + nt * 16 + lr] = f2bf(gelu_exact(ga[nt][reg] + bias));
      }
    }
    // sG rows m0..m0+15 written & read only by this wave: no barrier needed.
    #pragma unroll
    for (int s2 = 0; s2 < 2; ++s2) {
      bf16x8 ag = *(const bf16x8*)&sG[(m0 + lr) * SGPAD + s2 * 32 + lq * 8];
      #pragma unroll
      for (int nt = 0; nt < 16; ++nt) {
        bf16x8 b = *(const bf16x8*)&w2p[((long)(nt * 32 + f * 2 + s2) * 64 + ln) * 8];
        acc3[nt] = mfma16(ag, b, acc3[nt]);
      }
    }
  }
  #pragma unroll
  for (int nt = 0; nt < 16; ++nt) {
    const int col = nt * 16 + lr;
    const float bias = bff2[col];
    #pragma unroll
    for (int reg = 0; reg < 4; ++reg) {
      const int row = m0 + lq * 4 + reg;
      const long gi = (tokbase + row) * DIM + col;
      X[gi] = X[gi] + acc3[nt][reg] + bias;
    }
  }
}

// ---------------------------------------------------------------------------
// k_pool: masked mean pool + log1p(count) -> F PACKED bf16 [8192 x 320]
// ---------------------------------------------------------------------------
__global__ __launch_bounds__(256) void k_pool(
    const float* __restrict__ X, const int* __restrict__ NPICK,
    const float* __restrict__ count, unsigned short* __restrict__ Fp)
{
  const int tid = threadIdx.x;
  const int cc = tid >> 2, p = tid & 3;
  const int chain = blockIdx.x * 64 + cc;
  const int np = NPICK[chain];
  const float inv = (np > 0) ? (1.f / (float)np) : 0.f;
  const int rtile = chain >> 4, lr = chain & 15;
  const float4* xb = (const float4*)(X + (long)chain * KTOK * DIM + p * 64);
  #pragma unroll
  for (int i = 0; i < 16; i += 2) {
    float4 s0 = make_float4(0.f, 0.f, 0.f, 0.f);
    float4 s1 = make_float4(0.f, 0.f, 0.f, 0.f);
    for (int j = 0; j < np; ++j) {
      float4 t0 = xb[j * 64 + i];
      float4 t1 = xb[j * 64 + i + 1];
      s0.x += t0.x; s0.y += t0.y; s0.z += t0.z; s0.w += t0.w;
      s1.x += t1.x; s1.y += t1.y; s1.z += t1.z; s1.w += t1.w;
    }
    const int q = p * 8 + (i >> 1);
    const int s = q >> 2, lq = q & 3;
    u16x8 o;
    o[0] = f2bf(s0.x * inv); o[1] = f2bf(s0.y * inv);
    o[2] = f2bf(s0.z * inv); o[3] = f2bf(s0.w * inv);
    o[4] = f2bf(s1.x * inv); o[5] = f2bf(s1.y * inv);
    o[6] = f2bf(s1.z * inv); o[7] = f2bf(s1.w * inv);
    *(u16x8*)&Fp[((long)(rtile * 10 + s) * 64 + lq * 16 + lr) * 8] = o;
  }
  if (p == 3) {
    // tail cols 256..319: groups q=32..39 (s=8,9)
    #pragma unroll
    for (int q = 32; q < 40; ++q) {
      const int s = q >> 2, lq = q & 3;
      u16x8 o = {0,0,0,0,0,0,0,0};
      if (q == 32) o[0] = f2bf(log1pf(count[chain]));
      *(u16x8*)&Fp[((long)(rtile * 10 + s) * 64 + lq * 16 + lr) * 8] = o;
    }
  }
}

// ---------------------------------------------------------------------------
// k_headmlp: out = gelu(F@wout1p^T+b1)@wout2^T+b2. 64 chains/block.
// ---------------------------------------------------------------------------
__global__ __launch_bounds__(256, 3) void k_headmlp(
    const unsigned short* __restrict__ Fp,
    const unsigned short* __restrict__ wo1p, const unsigned short* __restrict__ wo2p,
    const float* __restrict__ bout1, const float* __restrict__ bout2,
    float* __restrict__ out)
{
  __shared__ unsigned short sG[64 * SGPAD];
  const int tid = threadIdx.x;
  const long rowbase = (long)blockIdx.x * 64;
  const int wv = tid >> 6, ln = tid & 63;
  const int lr = ln & 15, lq = ln >> 4;
  const int m0 = wv * 16;
  const int rtile = blockIdx.x * 4 + wv;
  const f32x4 vzero = {0.f, 0.f, 0.f, 0.f};

  bf16x8 af[10];
  #pragma unroll
  for (int s = 0; s < 10; ++s)
    af[s] = *(const bf16x8*)&Fp[((long)(rtile * 10 + s) * 64 + ln) * 8];

  f32x4 oacc[16];
  #pragma unroll
  for (int nt = 0; nt < 16; ++nt) oacc[nt] = vzero;

  for (int f = 0; f < 16; ++f) {
    f32x4 ga[4];
    #pragma unroll
    for (int nt = 0; nt < 4; ++nt) ga[nt] = vzero;
    #pragma unroll
    for (int s = 0; s < 10; ++s) {
      #pragma unroll
      for (int nt = 0; nt < 4; ++nt) {
        bf16x8 b = *(const bf16x8*)&wo1p[((long)((f * 4 + nt) * 10 + s) * 64 + ln) * 8];
        ga[nt] = mfma16(af[s], b, ga[nt]);
      }
    }
    #pragma unroll
    for (int nt = 0; nt < 4; ++nt) {
      const int n = f * 64 + nt * 16 + lr;
      const float bias = bout1[n];
      #pragma unroll
      for (int reg = 0; reg < 4; ++reg) {
        sG[(m0 + lq * 4 + reg) * SGPAD + nt * 16 + lr] = f2bf(gelu_exact(ga[nt][reg] + bias));
      }
    }
    // wave-private sG: no barrier
    #pragma unroll
    for (int s2 = 0; s2 < 2; ++s2) {
      bf16x8 ag = *(const bf16x8*)&sG[(m0 + lr) * SGPAD + s2 * 32 + lq * 8];
      #pragma unroll
      for (int nt = 0; nt < 16; ++nt) {
        bf16x8 b = *(const bf16x8*)&wo2p[((long)(nt * 32 + f * 2 + s2) * 64 + ln) * 8];
        oacc[nt] = mfma16(ag, b, oacc[nt]);
      }
    }
  }
  #pragma unroll
  for (int nt = 0; nt < 16; ++nt) {
    const int col = nt * 16 + lr;
    const float bias = bout2[col];
    #pragma unroll
    for (int reg = 0; reg < 4; ++reg) {
      const int row = m0 + lq * 4 + reg;
      out[(rowbase + row) * DIM + col] = oacc[nt][reg] + bias;
    }
  }
}

// ---------------------------------------------------------------------------
extern "C" void kernel_launch(void* const* d_in, const int* in_sizes, int n_in,
                              void* d_out, int out_size, void* d_ws, size_t ws_size,
                              hipStream_t stream) {
  (void)in_sizes; (void)n_in; (void)out_size; (void)ws_size;
  const float* v          = (const float*)d_in[0];
  const int*   batch_idx  = (const int*)  d_in[1];
  const int*   mask       = (const int*)  d_in[2];
  const float* count      = (const float*)d_in[3];
  const float* rank       = (const float*)d_in[4];
  const float* pe         = (const float*)d_in[5];
  const float* w_qkv      = (const float*)d_in[6];
  const float* b_qkv      = (const float*)d_in[7];
  const float* w_o        = (const float*)d_in[8];
  const float* b_o        = (const float*)d_in[9];
  const float* ln1g       = (const float*)d_in[10];
  const float* ln1b       = (const float*)d_in[11];
  const float* ln2g       = (const float*)d_in[12];
  const float* ln2b       = (const float*)d_in[13];
  const float* w_ff1      = (const float*)d_in[14];
  const float* b_ff1      = (const float*)d_in[15];
  const float* w_ff2      = (const float*)d_in[16];
  const float* b_ff2      = (const float*)d_in[17];
  const float* w_out1     = (const float*)d_in[18];
  const float* b_out1     = (const float*)d_in[19];
  const float* w_out2     = (const float*)d_in[20];
  const float* b_out2     = (const float*)d_in[21];
  float* out = (float*)d_out;

  char* ws = (char*)d_ws;
  float*          X     = (float*)ws;                              // 67,108,864
  unsigned short* H1p   = (unsigned short*)(ws + 67108864);        // 33,554,432 (H2p aliases)
  unsigned short* H2p   = H1p;                                     // H1 dead after k_attnfused
  unsigned short* Fp    = (unsigned short*)(ws + 100663296);       //  5,242,880
  int*            NPICK = (int*)(ws + 105906176);                  //     32,768
  unsigned short* wq_bf   = (unsigned short*)(ws + 105938944);     //    393,216
  unsigned short* wo_bf   = (unsigned short*)(ws + 106332160);     //    131,072
  unsigned short* wff1_bf = (unsigned short*)(ws + 106463232);     //    524,288
  unsigned short* wff2_bf = (unsigned short*)(ws + 106987520);     //    524,288
  unsigned short* wo1_bf  = (unsigned short*)(ws + 107511808);     //    655,360
  unsigned short* wo2_bf  = (unsigned short*)(ws + 108167168);     //    524,288 -> end 108,691,456

  k_prep<<<PREP_GROUPS / 256, 256, 0, stream>>>(
      w_qkv, w_o, w_ff1, w_ff2, w_out1, w_out2,
      wq_bf, wo_bf, wff1_bf, wff2_bf, wo1_bf, wo2_bf);

  k_sel<<<8192, 256, 0, stream>>>(v, batch_idx, mask, rank, pe,
                                  ln1g, ln1b, X, H1p, NPICK);

  k_attnfused<<<2048, 256, 0, stream>>>(H1p, X, NPICK, wq_bf, b_qkv, wo_bf, b_o);

  k_ln2<<<1024, 256, 0, stream>>>(X, ln2g, ln2b, H2p);

  k_ff<<<1024, 256, 0, stream>>>(X, H2p, wff1_bf, wff2_bf, b_ff1, b_ff2);

  k_pool<<<128, 256, 0, stream>>>(X, NPICK, count, Fp);

  k_headmlp<<<128, 256, 0, stream>>>(Fp, wo1_bf, wo2_bf, b_out1, b_out2, out);
}

// Round 4
// 850.561 us; speedup vs baseline: 1.7923x; 1.3757x over previous
//
#include <hip/hip_runtime.h>

// ============================================================================
// TransformerSubsetAggregator on MI355X (gfx950) — round 4
// Key change vs r3: weight GEMMs restructured so weights are staged into LDS
// once per 128-token block (8 waves share), via register-prefetch double
// buffer. Kills the 4 GB/launch private L2 weight streaming (r3: every wave
// streamed all weights; 16 FLOP/B -> L2-latency bound, MfmaUtil 5.6%).
// Pipeline: k_prep | k_sel(+LN1->H1p) | k_qkv | k_attn | k_oproj | k_ln2 |
//           k_ff | k_pool | k_headmlp
// ws ~195 MB: X 64 | Op(alias H1p) 32 | QKVp 96 (H2p+Fp alias after death) |
//             NPICK | packed weights ~2.7 MB
// ============================================================================

#define DIM   256
#define LSEQ  128
#define KTOK  8

typedef __bf16 bf16x8 __attribute__((ext_vector_type(8)));
typedef float  f32x4  __attribute__((ext_vector_type(4)));
typedef unsigned short u16x8 __attribute__((ext_vector_type(8)));

__device__ __forceinline__ f32x4 mfma16(bf16x8 a, bf16x8 b, f32x4 c) {
  // A/B frag: m(or n)=lane&15, k=(lane>>4)*8+j ; D: col=lane&15, row=(lane>>4)*4+reg
  return __builtin_amdgcn_mfma_f32_16x16x32_bf16(a, b, c, 0, 0, 0);
}

__device__ __forceinline__ unsigned short f2bf(float f) {
  unsigned u = __float_as_uint(f);
  u = (u + 0x7FFFu + ((u >> 16) & 1u)) >> 16;   // RNE
  return (unsigned short)u;
}

__device__ __forceinline__ float gelu_exact(float x) {
  return 0.5f * x * (1.f + erff(x * 0.70710678118654752f));
}

// ---- 32KB chunk staging: register prefetch + LDS commit (512-thread blocks)
struct Stage32 { u16x8 r[4]; };
__device__ __forceinline__ void stage_load(Stage32& st, const unsigned short* __restrict__ g, int tid) {
  #pragma unroll
  for (int i = 0; i < 4; ++i) st.r[i] = *(const u16x8*)&g[(tid + i * 512) * 8];
}
__device__ __forceinline__ void stage_commit(const Stage32& st, unsigned short* l, int tid) {
  #pragma unroll
  for (int i = 0; i < 4; ++i) *(u16x8*)&l[(tid + i * 512) * 8] = st.r[i];
}

// ---------------------------------------------------------------------------
// k_prep: pack weights fp32 -> bf16 fragment-major.
// n-major (KC): group (ntile*KC + s); k-major (NT): group (s*NT + ntile).
// ---------------------------------------------------------------------------
__device__ __forceinline__ void pack_region(
    const float* __restrict__ src, unsigned short* __restrict__ dst,
    int g, int KC, int Ksrc, int Klim)
{
  const int ln = g & 63;
  const int t = g >> 6;
  const int s = t % KC;
  const int ntile = t / KC;
  const int row = ntile * 16 + (ln & 15);
  const int c0 = s * 32 + (ln >> 4) * 8;
  u16x8 o;
  #pragma unroll
  for (int j = 0; j < 8; ++j) {
    float val = (c0 + j < Klim) ? src[(long)row * Ksrc + c0 + j] : 0.f;
    o[j] = f2bf(val);
  }
  *(u16x8*)&dst[(long)g * 8] = o;
}

__device__ __forceinline__ void pack_region_kmaj(
    const float* __restrict__ src, unsigned short* __restrict__ dst,
    int g, int NT, int Ksrc)
{
  const int ln = g & 63;
  const int t = g >> 6;
  const int ntile = t % NT;
  const int s = t / NT;
  const int row = ntile * 16 + (ln & 15);
  const int c0 = s * 32 + (ln >> 4) * 8;
  u16x8 o;
  #pragma unroll
  for (int j = 0; j < 8; ++j) o[j] = f2bf(src[(long)row * Ksrc + c0 + j]);
  *(u16x8*)&dst[(long)g * 8] = o;
}

#define PREP_GROUPS 172032
__global__ __launch_bounds__(256) void k_prep(
    const float* __restrict__ wqkv, const float* __restrict__ wo,
    const float* __restrict__ wff1, const float* __restrict__ wff2,
    const float* __restrict__ wout1, const float* __restrict__ wout2,
    unsigned short* __restrict__ oq, unsigned short* __restrict__ oo,
    unsigned short* __restrict__ of1, unsigned short* __restrict__ of2,
    unsigned short* __restrict__ oo1, unsigned short* __restrict__ oo2)
{
  int g = blockIdx.x * 256 + threadIdx.x;
  if (g < 24576) { pack_region(wqkv, oq, g, 8, 256, 256); return; }     // n-major
  g -= 24576;
  if (g < 8192)  { pack_region(wo, oo, g, 8, 256, 256); return; }       // n-major
  g -= 8192;
  if (g < 32768) { pack_region(wff1, of1, g, 8, 256, 256); return; }    // n-major (f-chunked)
  g -= 32768;
  if (g < 32768) { pack_region_kmaj(wff2, of2, g, 16, 1024); return; }  // k-major!
  g -= 32768;
  if (g < 40960) { pack_region(wout1, oo1, g, 10, 257, 257); return; }  // n-major
  g -= 40960;
  if (g < 32768) { pack_region(wout2, oo2, g, 32, 1024, 1024); }        // n-major
}

// ---------------------------------------------------------------------------
// k_sel: top-8 (lax.top_k ties: value desc, idx asc), sort picked idx asc,
// gather v + pos_embed -> X fp32 (row-major), fused LN1 -> H1 PACKED bf16.
// ---------------------------------------------------------------------------
__global__ __launch_bounds__(256) void k_sel(
    const float* __restrict__ v, const int* __restrict__ batch_idx,
    const int* __restrict__ mask, const float* __restrict__ rank_scores,
    const float* __restrict__ pos_embed,
    const float* __restrict__ ln1g, const float* __restrict__ ln1b,
    float* __restrict__ X, unsigned short* __restrict__ H1p,
    int* __restrict__ NPICK)
{
  const int c = blockIdx.x;
  const int tid = threadIdx.x;
  __shared__ int s_mem[KTOK];
  __shared__ int s_np;

  if (tid < 64) {
    const int l = tid;
    unsigned long long key[2];
    #pragma unroll
    for (int t = 0; t < 2; ++t) {
      int p = l + 64 * t;
      int mk = mask[c * LSEQ + p];
      float s = rank_scores[c * LSEQ + p];
      unsigned u = __float_as_uint(s);
      u = (u & 0x80000000u) ? ~u : (u | 0x80000000u);
      unsigned long long kk =
          ((unsigned long long)u << 32) | (unsigned long long)(0xFFFFFFFFu - (unsigned)p);
      key[t] = mk ? kk : 0ull;
    }
    int w[KTOK];
    #pragma unroll
    for (int r = 0; r < KTOK; ++r) w[r] = 0x7FFFFFFF;
    int np = 0;
    for (int r = 0; r < KTOK; ++r) {
      unsigned long long best = key[0] > key[1] ? key[0] : key[1];
      for (int off = 32; off > 0; off >>= 1) {
        unsigned long long o = __shfl_xor(best, off, 64);
        if (o > best) best = o;
      }
      if (best == 0ull) break;
      int idx = (int)(0xFFFFFFFFu - (unsigned)(best & 0xFFFFFFFFull));
      w[np++] = idx;
      if (key[0] == best) key[0] = 0ull;
      if (key[1] == best) key[1] = 0ull;
    }
    #pragma unroll
    for (int a = 0; a < KTOK - 1; ++a)
      #pragma unroll
      for (int b2 = 0; b2 < KTOK - 1 - a; ++b2) {
        int x0 = w[b2], x1 = w[b2 + 1];
        w[b2] = min(x0, x1); w[b2 + 1] = max(x0, x1);
      }
    if (l < KTOK) s_mem[l] = (l < np) ? batch_idx[c * LSEQ + w[l]] : -1;
    if (l == 0) { s_np = np; NPICK[c] = np; }
  }
  __syncthreads();

  const int np = s_np;
  const int j = tid >> 5, q = tid & 31;     // 32 threads/token, 8 cols each
  const int r = s_mem[j];
  const float4* v4  = (const float4*)v;
  const float4* pe4 = (const float4*)pos_embed;
  float4* X4 = (float4*)X;

  float4 xv[2];                              // cols q*8 .. q*8+7
  #pragma unroll
  for (int rep = 0; rep < 2; ++rep) {
    const int f = 2 * q + rep;
    float4 pe = pe4[j * 64 + f];
    float4 val = make_float4(0.f, 0.f, 0.f, 0.f);
    if (j < np) val = v4[(long)r * 64 + f];
    xv[rep].x = val.x + pe.x; xv[rep].y = val.y + pe.y;
    xv[rep].z = val.z + pe.z; xv[rep].w = val.w + pe.w;
    X4[((long)c * KTOK + j) * 64 + f] = xv[rep];
  }
  float sum = 0.f, ss = 0.f;
  #pragma unroll
  for (int rep = 0; rep < 2; ++rep) {
    sum += xv[rep].x + xv[rep].y + xv[rep].z + xv[rep].w;
    ss  += xv[rep].x * xv[rep].x + xv[rep].y * xv[rep].y
         + xv[rep].z * xv[rep].z + xv[rep].w * xv[rep].w;
  }
  #pragma unroll
  for (int off = 1; off <= 16; off <<= 1) {
    sum += __shfl_xor(sum, off); ss += __shfl_xor(ss, off);
  }
  const float mu = sum * (1.f / 256.f);
  const float var = ss * (1.f / 256.f) - mu * mu;
  const float rstd = rsqrtf(var + 1e-5f);
  const int t = c * KTOK + j;
  const int mtile = t >> 4, lr = t & 15;
  const int s = q >> 2, lq = q & 3;
  u16x8 o;
  const int col = q * 8;
  o[0] = f2bf((xv[0].x - mu) * rstd * ln1g[col + 0] + ln1b[col + 0]);
  o[1] = f2bf((xv[0].y - mu) * rstd * ln1g[col + 1] + ln1b[col + 1]);
  o[2] = f2bf((xv[0].z - mu) * rstd * ln1g[col + 2] + ln1b[col + 2]);
  o[3] = f2bf((xv[0].w - mu) * rstd * ln1g[col + 3] + ln1b[col + 3]);
  o[4] = f2bf((xv[1].x - mu) * rstd * ln1g[col + 4] + ln1b[col + 4]);
  o[5] = f2bf((xv[1].y - mu) * rstd * ln1g[col + 5] + ln1b[col + 5]);
  o[6] = f2bf((xv[1].z - mu) * rstd * ln1g[col + 6] + ln1b[col + 6]);
  o[7] = f2bf((xv[1].w - mu) * rstd * ln1g[col + 7] + ln1b[col + 7]);
  *(u16x8*)&H1p[((long)(mtile * 8 + s) * 64 + lq * 16 + lr) * 8] = o;
}

// ---------------------------------------------------------------------------
// k_qkv: QKV GEMM, M=65536, N=768, K=256. 512 thr = 8 waves = 128 tokens.
// Weights staged 32KB/chunk into LDS (shared by 8 waves), reg double-buffer.
// Output QKVp row-major bf16 [65536][768].
// ---------------------------------------------------------------------------
__global__ __launch_bounds__(512, 4) void k_qkv(
    const unsigned short* __restrict__ H1p, unsigned short* __restrict__ QKVp,
    const unsigned short* __restrict__ wqp, const float* __restrict__ bqkv)
{
  __shared__ unsigned short buf[16384];      // 32 KB
  const int tid = threadIdx.x;
  const int wv = tid >> 6, ln = tid & 63;
  const int lr = ln & 15, lq = ln >> 4;
  const int mtile = blockIdx.x * 8 + wv;
  const f32x4 vzero = {0.f, 0.f, 0.f, 0.f};

  bf16x8 af[8];
  #pragma unroll
  for (int s = 0; s < 8; ++s)
    af[s] = *(const bf16x8*)&H1p[((long)(mtile * 8 + s) * 64 + ln) * 8];

  Stage32 st;
  stage_load(st, wqp, tid);
  for (int c = 0; c < 12; ++c) {
    stage_commit(st, buf, tid);
    __syncthreads();
    if (c < 11) stage_load(st, wqp + (c + 1) * 16384, tid);
    f32x4 acc[4];
    #pragma unroll
    for (int nt = 0; nt < 4; ++nt) acc[nt] = vzero;
    #pragma unroll
    for (int s = 0; s < 8; ++s) {
      #pragma unroll
      for (int nt = 0; nt < 4; ++nt) {
        bf16x8 b = *(const bf16x8*)&buf[(nt * 8 + s) * 512 + ln * 8];
        acc[nt] = mfma16(af[s], b, acc[nt]);
      }
    }
    #pragma unroll
    for (int nt = 0; nt < 4; ++nt) {
      const int col = c * 64 + nt * 16 + lr;
      const float bias = bqkv[col];
      #pragma unroll
      for (int reg = 0; reg < 4; ++reg) {
        const int row = mtile * 16 + lq * 4 + reg;
        QKVp[(long)row * 768 + col] = f2bf(acc[nt][reg] + bias);
      }
    }
    __syncthreads();
  }
}

// ---------------------------------------------------------------------------
// k_attn: 4 chains (32 tokens)/block; stage QKV tile, softmax-attention,
// write O in PACKED A-fragment layout for k_oproj.
// ---------------------------------------------------------------------------
#define SQV 776   // 768 + 8

__global__ __launch_bounds__(256, 3) void k_attn(
    const unsigned short* __restrict__ QKVp, const int* __restrict__ NPICK,
    unsigned short* __restrict__ Op)
{
  __shared__ unsigned short sQKV[32 * SQV];
  __shared__ int s_np[4];
  const int tid = threadIdx.x;
  const int blk = blockIdx.x;
  if (tid < 4) s_np[tid] = NPICK[blk * 4 + tid];
  for (int i = tid; i < 3072; i += 256) {
    const int r = i / 96, u = i - r * 96;
    *(u16x8*)&sQKV[r * SQV + u * 8] =
        *(const u16x8*)&QKVp[((long)blk * 32 + r) * 768 + u * 8];
  }
  __syncthreads();
  if (tid >= 128) return;

  const int c = tid >> 5, hh = (tid >> 3) & 3, qi = tid & 7;
  const int natt = max(1, s_np[c]);
  const int qrow = c * 8 + qi;
  float sc[8];
  #pragma unroll
  for (int j = 0; j < 8; ++j) sc[j] = -1e30f;
  for (int j = 0; j < natt; ++j) {
    float d = 0.f;
    #pragma unroll
    for (int dc = 0; dc < 8; ++dc) {
      bf16x8 qv = *(const bf16x8*)&sQKV[qrow * SQV + hh * 64 + dc * 8];
      bf16x8 kv = *(const bf16x8*)&sQKV[(c * 8 + j) * SQV + 256 + hh * 64 + dc * 8];
      #pragma unroll
      for (int e = 0; e < 8; ++e) d += (float)qv[e] * (float)kv[e];
    }
    sc[j] = d * 0.125f;
  }
  float mx = -1e30f;
  #pragma unroll
  for (int j = 0; j < 8; ++j) mx = fmaxf(mx, sc[j]);
  float pr[8]; float ssum = 0.f;
  #pragma unroll
  for (int j = 0; j < 8; ++j) {
    float e = (j < natt) ? __expf(sc[j] - mx) : 0.f;
    pr[j] = e; ssum += e;
  }
  const float inv = 1.f / ssum;
  const int t = blk * 32 + qrow;
  const int mt = t >> 4, lrt = t & 15;
  #pragma unroll
  for (int dc = 0; dc < 8; ++dc) {
    float o8[8] = {0.f,0.f,0.f,0.f,0.f,0.f,0.f,0.f};
    for (int j = 0; j < natt; ++j) {
      const float pj = pr[j] * inv;
      bf16x8 vv = *(const bf16x8*)&sQKV[(c * 8 + j) * SQV + 512 + hh * 64 + dc * 8];
      #pragma unroll
      for (int e = 0; e < 8; ++e) o8[e] += pj * (float)vv[e];
    }
    u16x8 o;
    #pragma unroll
    for (int e = 0; e < 8; ++e) o[e] = f2bf(o8[e]);
    const int s = hh * 2 + (dc >> 2), lqt = dc & 3;
    *(u16x8*)&Op[((long)(mt * 8 + s) * 64 + lqt * 16 + lrt) * 8] = o;
  }
}

// ---------------------------------------------------------------------------
// k_oproj: X += O @ wo^T + bo. Same staged template as k_qkv (N=256 -> 4 chunks).
// ---------------------------------------------------------------------------
__global__ __launch_bounds__(512, 4) void k_oproj(
    const unsigned short* __restrict__ Op, float* __restrict__ X,
    const unsigned short* __restrict__ wop, const float* __restrict__ bo)
{
  __shared__ unsigned short buf[16384];
  const int tid = threadIdx.x;
  const int wv = tid >> 6, ln = tid & 63;
  const int lr = ln & 15, lq = ln >> 4;
  const int mtile = blockIdx.x * 8 + wv;
  const f32x4 vzero = {0.f, 0.f, 0.f, 0.f};

  bf16x8 af[8];
  #pragma unroll
  for (int s = 0; s < 8; ++s)
    af[s] = *(const bf16x8*)&Op[((long)(mtile * 8 + s) * 64 + ln) * 8];

  Stage32 st;
  stage_load(st, wop, tid);
  for (int c = 0; c < 4; ++c) {
    stage_commit(st, buf, tid);
    __syncthreads();
    if (c < 3) stage_load(st, wop + (c + 1) * 16384, tid);
    f32x4 acc[4];
    #pragma unroll
    for (int nt = 0; nt < 4; ++nt) acc[nt] = vzero;
    #pragma unroll
    for (int s = 0; s < 8; ++s) {
      #pragma unroll
      for (int nt = 0; nt < 4; ++nt) {
        bf16x8 b = *(const bf16x8*)&buf[(nt * 8 + s) * 512 + ln * 8];
        acc[nt] = mfma16(af[s], b, acc[nt]);
      }
    }
    #pragma unroll
    for (int nt = 0; nt < 4; ++nt) {
      const int col = c * 64 + nt * 16 + lr;
      const float bias = bo[col];
      #pragma unroll
      for (int reg = 0; reg < 4; ++reg) {
        const int row = mtile * 16 + lq * 4 + reg;
        const long gi = (long)row * DIM + col;
        X[gi] = X[gi] + acc[nt][reg] + bias;
      }
    }
    __syncthreads();
  }
}

// ---------------------------------------------------------------------------
// k_ln2: X fp32 -> H2 PACKED bf16 (64 rows/block, 4 threads/row)
// ---------------------------------------------------------------------------
__global__ __launch_bounds__(256) void k_ln2(
    const float* __restrict__ X, const float* __restrict__ g,
    const float* __restrict__ b, unsigned short* __restrict__ H2p)
{
  const int tid = threadIdx.x;
  const int row = blockIdx.x * 64 + (tid >> 2);
  const int p = tid & 3;
  const float4* xr = (const float4*)(X + (long)row * DIM + p * 64);
  float4 xv[16];
  float sum = 0.f, ss = 0.f;
  #pragma unroll
  for (int i = 0; i < 16; ++i) {
    xv[i] = xr[i];
    sum += xv[i].x + xv[i].y + xv[i].z + xv[i].w;
    ss  += xv[i].x * xv[i].x + xv[i].y * xv[i].y + xv[i].z * xv[i].z + xv[i].w * xv[i].w;
  }
  sum += __shfl_xor(sum, 1); ss += __shfl_xor(ss, 1);
  sum += __shfl_xor(sum, 2); ss += __shfl_xor(ss, 2);
  const float mu = sum * (1.f / 256.f);
  const float var = ss * (1.f / 256.f) - mu * mu;
  const float rstd = rsqrtf(var + 1e-5f);
  const int mtile = row >> 4, lr = row & 15;
  #pragma unroll
  for (int i = 0; i < 16; i += 2) {
    const int q = p * 8 + (i >> 1);
    const int s = q >> 2, lq = q & 3;
    const int col = q * 8;
    u16x8 o;
    o[0] = f2bf((xv[i].x - mu) * rstd * g[col + 0] + b[col + 0]);
    o[1] = f2bf((xv[i].y - mu) * rstd * g[col + 1] + b[col + 1]);
    o[2] = f2bf((xv[i].z - mu) * rstd * g[col + 2] + b[col + 2]);
    o[3] = f2bf((xv[i].w - mu) * rstd * g[col + 3] + b[col + 3]);
    o[4] = f2bf((xv[i+1].x - mu) * rstd * g[col + 4] + b[col + 4]);
    o[5] = f2bf((xv[i+1].y - mu) * rstd * g[col + 5] + b[col + 5]);
    o[6] = f2bf((xv[i+1].z - mu) * rstd * g[col + 6] + b[col + 6]);
    o[7] = f2bf((xv[i+1].w - mu) * rstd * g[col + 7] + b[col + 7]);
    *(u16x8*)&H2p[((long)(mtile * 8 + s) * 64 + lq * 16 + lr) * 8] = o;
  }
}

// ---------------------------------------------------------------------------
// k_ff: x += gelu(h2@wff1^T+b1)@wff2^T+b2. 512 thr = 8 waves = 128 tokens.
// Per f-chunk: stage w1[f] (32KB) + w2[f] (32KB, k-major) into LDS shared by
// all waves; wave-private sG transpose, no barrier between FF1 and FF2.
// LDS 82 KB -> 1 block/CU (8 waves).
// ---------------------------------------------------------------------------
#define SGPAD 72    // 64+8

__global__ __launch_bounds__(512, 2) void k_ff(
    float* __restrict__ X, const unsigned short* __restrict__ H2p,
    const unsigned short* __restrict__ w1p, const unsigned short* __restrict__ w2p,
    const float* __restrict__ bff1, const float* __restrict__ bff2)
{
  __shared__ unsigned short bufA[16384];   // 32 KB: w1[f]
  __shared__ unsigned short bufB[16384];   // 32 KB: w2[f]
  __shared__ unsigned short sG[128 * SGPAD];
  const int tid = threadIdx.x;
  const int wv = tid >> 6, ln = tid & 63;
  const int lr = ln & 15, lq = ln >> 4;
  const int m0 = wv * 16;
  const int mtile = blockIdx.x * 8 + wv;
  const f32x4 vzero = {0.f, 0.f, 0.f, 0.f};

  bf16x8 af[8];
  #pragma unroll
  for (int s = 0; s < 8; ++s)
    af[s] = *(const bf16x8*)&H2p[((long)(mtile * 8 + s) * 64 + ln) * 8];

  f32x4 acc3[16];
  #pragma unroll
  for (int nt = 0; nt < 16; ++nt) acc3[nt] = vzero;

  Stage32 stA, stB;
  stage_load(stA, w1p, tid);
  stage_load(stB, w2p, tid);

  for (int f = 0; f < 16; ++f) {
    stage_commit(stA, bufA, tid);
    stage_commit(stB, bufB, tid);
    __syncthreads();
    if (f < 15) {
      stage_load(stA, w1p + (f + 1) * 16384, tid);
      stage_load(stB, w2p + (f + 1) * 16384, tid);
    }
    // FF1: 64 FF-cols for this f
    f32x4 ga[4];
    #pragma unroll
    for (int nt = 0; nt < 4; ++nt) ga[nt] = vzero;
    #pragma unroll
    for (int s = 0; s < 8; ++s) {
      #pragma unroll
      for (int nt = 0; nt < 4; ++nt) {
        bf16x8 b = *(const bf16x8*)&bufA[(nt * 8 + s) * 512 + ln * 8];
        ga[nt] = mfma16(af[s], b, ga[nt]);
      }
    }
    // gelu -> sG (wave-private rows m0..m0+15): no barrier needed
    #pragma unroll
    for (int nt = 0; nt < 4; ++nt) {
      const int n = f * 64 + nt * 16 + lr;
      const float bias = bff1[n];
      #pragma unroll
      for (int reg = 0; reg < 4; ++reg) {
        sG[(m0 + lq * 4 + reg) * SGPAD + nt * 16 + lr] = f2bf(gelu_exact(ga[nt][reg] + bias));
      }
    }
    // FF2 partial: K-slice f*64..f*64+63
    #pragma unroll
    for (int s2 = 0; s2 < 2; ++s2) {
      bf16x8 ag = *(const bf16x8*)&sG[(m0 + lr) * SGPAD + s2 * 32 + lq * 8];
      #pragma unroll
      for (int nt = 0; nt < 16; ++nt) {
        bf16x8 b = *(const bf16x8*)&bufB[(s2 * 16 + nt) * 512 + ln * 8];
        acc3[nt] = mfma16(ag, b, acc3[nt]);
      }
    }
    __syncthreads();
  }
  #pragma unroll
  for (int nt = 0; nt < 16; ++nt) {
    const int col = nt * 16 + lr;
    const float bias = bff2[col];
    #pragma unroll
    for (int reg = 0; reg < 4; ++reg) {
      const int row = mtile * 16 + lq * 4 + reg;
      const long gi = (long)row * DIM + col;
      X[gi] = X[gi] + acc3[nt][reg] + bias;
    }
  }
}

// ---------------------------------------------------------------------------
// k_pool: masked mean pool + log1p(count) -> F PACKED bf16 [8192 x 320]
// ---------------------------------------------------------------------------
__global__ __launch_bounds__(256) void k_pool(
    const float* __restrict__ X, const int* __restrict__ NPICK,
    const float* __restrict__ count, unsigned short* __restrict__ Fp)
{
  const int tid = threadIdx.x;
  const int cc = tid >> 2, p = tid & 3;
  const int chain = blockIdx.x * 64 + cc;
  const int np = NPICK[chain];
  const float inv = (np > 0) ? (1.f / (float)np) : 0.f;
  const int rtile = chain >> 4, lr = chain & 15;
  const float4* xb = (const float4*)(X + (long)chain * KTOK * DIM + p * 64);
  #pragma unroll
  for (int i = 0; i < 16; i += 2) {
    float4 s0 = make_float4(0.f, 0.f, 0.f, 0.f);
    float4 s1 = make_float4(0.f, 0.f, 0.f, 0.f);
    for (int j = 0; j < np; ++j) {
      float4 t0 = xb[j * 64 + i];
      float4 t1 = xb[j * 64 + i + 1];
      s0.x += t0.x; s0.y += t0.y; s0.z += t0.z; s0.w += t0.w;
      s1.x += t1.x; s1.y += t1.y; s1.z += t1.z; s1.w += t1.w;
    }
    const int q = p * 8 + (i >> 1);
    const int s = q >> 2, lq = q & 3;
    u16x8 o;
    o[0] = f2bf(s0.x * inv); o[1] = f2bf(s0.y * inv);
    o[2] = f2bf(s0.z * inv); o[3] = f2bf(s0.w * inv);
    o[4] = f2bf(s1.x * inv); o[5] = f2bf(s1.y * inv);
    o[6] = f2bf(s1.z * inv); o[7] = f2bf(s1.w * inv);
    *(u16x8*)&Fp[((long)(rtile * 10 + s) * 64 + lq * 16 + lr) * 8] = o;
  }
  if (p == 3) {
    #pragma unroll
    for (int q = 32; q < 40; ++q) {
      const int s = q >> 2, lq = q & 3;
      u16x8 o = {0,0,0,0,0,0,0,0};
      if (q == 32) o[0] = f2bf(log1pf(count[chain]));
      *(u16x8*)&Fp[((long)(rtile * 10 + s) * 64 + lq * 16 + lr) * 8] = o;
    }
  }
}

// ---------------------------------------------------------------------------
// k_headmlp: out = gelu(F@wout1p^T+b1)@wout2^T+b2. 64 chains/block.
// ---------------------------------------------------------------------------
__global__ __launch_bounds__(256, 3) void k_headmlp(
    const unsigned short* __restrict__ Fp,
    const unsigned short* __restrict__ wo1p, const unsigned short* __restrict__ wo2p,
    const float* __restrict__ bout1, const float* __restrict__ bout2,
    float* __restrict__ out)
{
  __shared__ unsigned short sG[64 * SGPAD];
  const int tid = threadIdx.x;
  const long rowbase = (long)blockIdx.x * 64;
  const int wv = tid >> 6, ln = tid & 63;
  const int lr = ln & 15, lq = ln >> 4;
  const int m0 = wv * 16;
  const int rtile = blockIdx.x * 4 + wv;
  const f32x4 vzero = {0.f, 0.f, 0.f, 0.f};

  bf16x8 af[10];
  #pragma unroll
  for (int s = 0; s < 10; ++s)
    af[s] = *(const bf16x8*)&Fp[((long)(rtile * 10 + s) * 64 + ln) * 8];

  f32x4 oacc[16];
  #pragma unroll
  for (int nt = 0; nt < 16; ++nt) oacc[nt] = vzero;

  for (int f = 0; f < 16; ++f) {
    f32x4 ga[4];
    #pragma unroll
    for (int nt = 0; nt < 4; ++nt) ga[nt] = vzero;
    #pragma unroll
    for (int s = 0; s < 10; ++s) {
      #pragma unroll
      for (int nt = 0; nt < 4; ++nt) {
        bf16x8 b = *(const bf16x8*)&wo1p[((long)((f * 4 + nt) * 10 + s) * 64 + ln) * 8];
        ga[nt] = mfma16(af[s], b, ga[nt]);
      }
    }
    #pragma unroll
    for (int nt = 0; nt < 4; ++nt) {
      const int n = f * 64 + nt * 16 + lr;
      const float bias = bout1[n];
      #pragma unroll
      for (int reg = 0; reg < 4; ++reg) {
        sG[(m0 + lq * 4 + reg) * SGPAD + nt * 16 + lr] = f2bf(gelu_exact(ga[nt][reg] + bias));
      }
    }
    #pragma unroll
    for (int s2 = 0; s2 < 2; ++s2) {
      bf16x8 ag = *(const bf16x8*)&sG[(m0 + lr) * SGPAD + s2 * 32 + lq * 8];
      #pragma unroll
      for (int nt = 0; nt < 16; ++nt) {
        bf16x8 b = *(const bf16x8*)&wo2p[((long)(nt * 32 + f * 2 + s2) * 64 + ln) * 8];
        oacc[nt] = mfma16(ag, b, oacc[nt]);
      }
    }
  }
  #pragma unroll
  for (int nt = 0; nt < 16; ++nt) {
    const int col = nt * 16 + lr;
    const float bias = bout2[col];
    #pragma unroll
    for (int reg = 0; reg < 4; ++reg) {
      const int row = m0 + lq * 4 + reg;
      out[(rowbase + row) * DIM + col] = oacc[nt][reg] + bias;
    }
  }
}

// ---------------------------------------------------------------------------
extern "C" void kernel_launch(void* const* d_in, const int* in_sizes, int n_in,
                              void* d_out, int out_size, void* d_ws, size_t ws_size,
                              hipStream_t stream) {
  (void)in_sizes; (void)n_in; (void)out_size; (void)ws_size;
  const float* v          = (const float*)d_in[0];
  const int*   batch_idx  = (const int*)  d_in[1];
  const int*   mask       = (const int*)  d_in[2];
  const float* count      = (const float*)d_in[3];
  const float* rank       = (const float*)d_in[4];
  const float* pe         = (const float*)d_in[5];
  const float* w_qkv      = (const float*)d_in[6];
  const float* b_qkv      = (const float*)d_in[7];
  const float* w_o        = (const float*)d_in[8];
  const float* b_o        = (const float*)d_in[9];
  const float* ln1g       = (const float*)d_in[10];
  const float* ln1b       = (const float*)d_in[11];
  const float* ln2g       = (const float*)d_in[12];
  const float* ln2b       = (const float*)d_in[13];
  const float* w_ff1      = (const float*)d_in[14];
  const float* b_ff1      = (const float*)d_in[15];
  const float* w_ff2      = (const float*)d_in[16];
  const float* b_ff2      = (const float*)d_in[17];
  const float* w_out1     = (const float*)d_in[18];
  const float* b_out1     = (const float*)d_in[19];
  const float* w_out2     = (const float*)d_in[20];
  const float* b_out2     = (const float*)d_in[21];
  float* out = (float*)d_out;

  char* ws = (char*)d_ws;
  float*          X     = (float*)ws;                              // 67,108,864
  unsigned short* H1p   = (unsigned short*)(ws + 67108864);        // 33,554,432
  unsigned short* Op    = H1p;                                     // alias: H1p dead after k_qkv
  unsigned short* QKVp  = (unsigned short*)(ws + 100663296);       // 100,663,296 (65536x768 bf16)
  unsigned short* H2p   = QKVp;                                    // alias: QKVp dead after k_attn
  unsigned short* Fp    = (unsigned short*)(ws + 134217728);       // alias inside QKVp region
  int*            NPICK = (int*)(ws + 201326592);                  //     32,768
  unsigned short* wq_bf   = (unsigned short*)(ws + 201359360);     //    393,216
  unsigned short* wo_bf   = (unsigned short*)(ws + 201752576);     //    131,072
  unsigned short* wff1_bf = (unsigned short*)(ws + 201883648);     //    524,288
  unsigned short* wff2_bf = (unsigned short*)(ws + 202407936);     //    524,288 (k-major)
  unsigned short* wo1_bf  = (unsigned short*)(ws + 202932224);     //    655,360
  unsigned short* wo2_bf  = (unsigned short*)(ws + 203587584);     //    524,288 -> end 204,111,872

  k_prep<<<PREP_GROUPS / 256, 256, 0, stream>>>(
      w_qkv, w_o, w_ff1, w_ff2, w_out1, w_out2,
      wq_bf, wo_bf, wff1_bf, wff2_bf, wo1_bf, wo2_bf);

  k_sel<<<8192, 256, 0, stream>>>(v, batch_idx, mask, rank, pe,
                                  ln1g, ln1b, X, H1p, NPICK);

  k_qkv<<<512, 512, 0, stream>>>(H1p, QKVp, wq_bf, b_qkv);

  k_attn<<<2048, 256, 0, stream>>>(QKVp, NPICK, Op);

  k_oproj<<<512, 512, 0, stream>>>(Op, X, wo_bf, b_o);

  k_ln2<<<1024, 256, 0, stream>>>(X, ln2g, ln2b, H2p);

  k_ff<<<512, 512, 0, stream>>>(X, H2p, wff1_bf, wff2_bf, b_ff1, b_ff2);

  k_pool<<<128, 256, 0, stream>>>(X, NPICK, count, Fp);

  k_headmlp<<<128, 256, 0, stream>>>(Fp, wo1_bf, wo2_bf, b_out1, b_out2, out);
}

// Round 5
// 634.141 us; speedup vs baseline: 2.4039x; 1.3413x over previous
//
#include <hip/hip_runtime.h>

// ============================================================================
// TransformerSubsetAggregator on MI355X (gfx950) — round 5
// vs r4: k_headmlp restructured (was 285 µs = 1/3 of total): staged weights
// (r3 lesson) + split-K over 4 FF-quarters -> 256 blocks (grid lesson),
// atomicAdd fp32 partials into memset-zeroed out. k_pool widened to 256 blks.
// Pipeline: k_prep | k_sel(+LN1->H1p) | k_qkv | k_attn | k_oproj | k_ln2 |
//           k_ff | k_pool | memset(out) | k_headmlp
// ============================================================================

#define DIM   256
#define LSEQ  128
#define KTOK  8

typedef __bf16 bf16x8 __attribute__((ext_vector_type(8)));
typedef float  f32x4  __attribute__((ext_vector_type(4)));
typedef unsigned short u16x8 __attribute__((ext_vector_type(8)));

__device__ __forceinline__ f32x4 mfma16(bf16x8 a, bf16x8 b, f32x4 c) {
  // A/B frag: m(or n)=lane&15, k=(lane>>4)*8+j ; D: col=lane&15, row=(lane>>4)*4+reg
  return __builtin_amdgcn_mfma_f32_16x16x32_bf16(a, b, c, 0, 0, 0);
}

__device__ __forceinline__ unsigned short f2bf(float f) {
  unsigned u = __float_as_uint(f);
  u = (u + 0x7FFFu + ((u >> 16) & 1u)) >> 16;   // RNE
  return (unsigned short)u;
}

__device__ __forceinline__ float gelu_exact(float x) {
  return 0.5f * x * (1.f + erff(x * 0.70710678118654752f));
}

// ---- 32KB chunk staging: register prefetch + LDS commit (512-thread blocks)
struct Stage32 { u16x8 r[4]; };
__device__ __forceinline__ void stage_load(Stage32& st, const unsigned short* __restrict__ g, int tid) {
  #pragma unroll
  for (int i = 0; i < 4; ++i) st.r[i] = *(const u16x8*)&g[(tid + i * 512) * 8];
}
__device__ __forceinline__ void stage_commit(const Stage32& st, unsigned short* l, int tid) {
  #pragma unroll
  for (int i = 0; i < 4; ++i) *(u16x8*)&l[(tid + i * 512) * 8] = st.r[i];
}

// ---------------------------------------------------------------------------
// k_prep: pack weights fp32 -> bf16 fragment-major.
// n-major (KC): group (ntile*KC + s); k-major (NT): group (s*NT + ntile).
// ---------------------------------------------------------------------------
__device__ __forceinline__ void pack_region(
    const float* __restrict__ src, unsigned short* __restrict__ dst,
    int g, int KC, int Ksrc, int Klim)
{
  const int ln = g & 63;
  const int t = g >> 6;
  const int s = t % KC;
  const int ntile = t / KC;
  const int row = ntile * 16 + (ln & 15);
  const int c0 = s * 32 + (ln >> 4) * 8;
  u16x8 o;
  #pragma unroll
  for (int j = 0; j < 8; ++j) {
    float val = (c0 + j < Klim) ? src[(long)row * Ksrc + c0 + j] : 0.f;
    o[j] = f2bf(val);
  }
  *(u16x8*)&dst[(long)g * 8] = o;
}

__device__ __forceinline__ void pack_region_kmaj(
    const float* __restrict__ src, unsigned short* __restrict__ dst,
    int g, int NT, int Ksrc)
{
  const int ln = g & 63;
  const int t = g >> 6;
  const int ntile = t % NT;
  const int s = t / NT;
  const int row = ntile * 16 + (ln & 15);
  const int c0 = s * 32 + (ln >> 4) * 8;
  u16x8 o;
  #pragma unroll
  for (int j = 0; j < 8; ++j) o[j] = f2bf(src[(long)row * Ksrc + c0 + j]);
  *(u16x8*)&dst[(long)g * 8] = o;
}

#define PREP_GROUPS 172032
__global__ __launch_bounds__(256) void k_prep(
    const float* __restrict__ wqkv, const float* __restrict__ wo,
    const float* __restrict__ wff1, const float* __restrict__ wff2,
    const float* __restrict__ wout1, const float* __restrict__ wout2,
    unsigned short* __restrict__ oq, unsigned short* __restrict__ oo,
    unsigned short* __restrict__ of1, unsigned short* __restrict__ of2,
    unsigned short* __restrict__ oo1, unsigned short* __restrict__ oo2)
{
  int g = blockIdx.x * 256 + threadIdx.x;
  if (g < 24576) { pack_region(wqkv, oq, g, 8, 256, 256); return; }     // n-major
  g -= 24576;
  if (g < 8192)  { pack_region(wo, oo, g, 8, 256, 256); return; }       // n-major
  g -= 8192;
  if (g < 32768) { pack_region(wff1, of1, g, 8, 256, 256); return; }    // n-major (f-chunked)
  g -= 32768;
  if (g < 32768) { pack_region_kmaj(wff2, of2, g, 16, 1024); return; }  // k-major
  g -= 32768;
  if (g < 40960) { pack_region(wout1, oo1, g, 10, 257, 257); return; }  // n-major (f-chunked)
  g -= 40960;
  if (g < 32768) { pack_region_kmaj(wout2, oo2, g, 16, 1024); }         // k-major (changed!)
}

// ---------------------------------------------------------------------------
// k_sel: top-8 (lax.top_k ties: value desc, idx asc), sort picked idx asc,
// gather v + pos_embed -> X fp32 (row-major), fused LN1 -> H1 PACKED bf16.
// ---------------------------------------------------------------------------
__global__ __launch_bounds__(256) void k_sel(
    const float* __restrict__ v, const int* __restrict__ batch_idx,
    const int* __restrict__ mask, const float* __restrict__ rank_scores,
    const float* __restrict__ pos_embed,
    const float* __restrict__ ln1g, const float* __restrict__ ln1b,
    float* __restrict__ X, unsigned short* __restrict__ H1p,
    int* __restrict__ NPICK)
{
  const int c = blockIdx.x;
  const int tid = threadIdx.x;
  __shared__ int s_mem[KTOK];
  __shared__ int s_np;

  if (tid < 64) {
    const int l = tid;
    unsigned long long key[2];
    #pragma unroll
    for (int t = 0; t < 2; ++t) {
      int p = l + 64 * t;
      int mk = mask[c * LSEQ + p];
      float s = rank_scores[c * LSEQ + p];
      unsigned u = __float_as_uint(s);
      u = (u & 0x80000000u) ? ~u : (u | 0x80000000u);
      unsigned long long kk =
          ((unsigned long long)u << 32) | (unsigned long long)(0xFFFFFFFFu - (unsigned)p);
      key[t] = mk ? kk : 0ull;
    }
    int w[KTOK];
    #pragma unroll
    for (int r = 0; r < KTOK; ++r) w[r] = 0x7FFFFFFF;
    int np = 0;
    for (int r = 0; r < KTOK; ++r) {
      unsigned long long best = key[0] > key[1] ? key[0] : key[1];
      for (int off = 32; off > 0; off >>= 1) {
        unsigned long long o = __shfl_xor(best, off, 64);
        if (o > best) best = o;
      }
      if (best == 0ull) break;
      int idx = (int)(0xFFFFFFFFu - (unsigned)(best & 0xFFFFFFFFull));
      w[np++] = idx;
      if (key[0] == best) key[0] = 0ull;
      if (key[1] == best) key[1] = 0ull;
    }
    #pragma unroll
    for (int a = 0; a < KTOK - 1; ++a)
      #pragma unroll
      for (int b2 = 0; b2 < KTOK - 1 - a; ++b2) {
        int x0 = w[b2], x1 = w[b2 + 1];
        w[b2] = min(x0, x1); w[b2 + 1] = max(x0, x1);
      }
    if (l < KTOK) s_mem[l] = (l < np) ? batch_idx[c * LSEQ + w[l]] : -1;
    if (l == 0) { s_np = np; NPICK[c] = np; }
  }
  __syncthreads();

  const int np = s_np;
  const int j = tid >> 5, q = tid & 31;     // 32 threads/token, 8 cols each
  const int r = s_mem[j];
  const float4* v4  = (const float4*)v;
  const float4* pe4 = (const float4*)pos_embed;
  float4* X4 = (float4*)X;

  float4 xv[2];                              // cols q*8 .. q*8+7
  #pragma unroll
  for (int rep = 0; rep < 2; ++rep) {
    const int f = 2 * q + rep;
    float4 pe = pe4[j * 64 + f];
    float4 val = make_float4(0.f, 0.f, 0.f, 0.f);
    if (j < np) val = v4[(long)r * 64 + f];
    xv[rep].x = val.x + pe.x; xv[rep].y = val.y + pe.y;
    xv[rep].z = val.z + pe.z; xv[rep].w = val.w + pe.w;
    X4[((long)c * KTOK + j) * 64 + f] = xv[rep];
  }
  float sum = 0.f, ss = 0.f;
  #pragma unroll
  for (int rep = 0; rep < 2; ++rep) {
    sum += xv[rep].x + xv[rep].y + xv[rep].z + xv[rep].w;
    ss  += xv[rep].x * xv[rep].x + xv[rep].y * xv[rep].y
         + xv[rep].z * xv[rep].z + xv[rep].w * xv[rep].w;
  }
  #pragma unroll
  for (int off = 1; off <= 16; off <<= 1) {
    sum += __shfl_xor(sum, off); ss += __shfl_xor(ss, off);
  }
  const float mu = sum * (1.f / 256.f);
  const float var = ss * (1.f / 256.f) - mu * mu;
  const float rstd = rsqrtf(var + 1e-5f);
  const int t = c * KTOK + j;
  const int mtile = t >> 4, lr = t & 15;
  const int s = q >> 2, lq = q & 3;
  u16x8 o;
  const int col = q * 8;
  o[0] = f2bf((xv[0].x - mu) * rstd * ln1g[col + 0] + ln1b[col + 0]);
  o[1] = f2bf((xv[0].y - mu) * rstd * ln1g[col + 1] + ln1b[col + 1]);
  o[2] = f2bf((xv[0].z - mu) * rstd * ln1g[col + 2] + ln1b[col + 2]);
  o[3] = f2bf((xv[0].w - mu) * rstd * ln1g[col + 3] + ln1b[col + 3]);
  o[4] = f2bf((xv[1].x - mu) * rstd * ln1g[col + 4] + ln1b[col + 4]);
  o[5] = f2bf((xv[1].y - mu) * rstd * ln1g[col + 5] + ln1b[col + 5]);
  o[6] = f2bf((xv[1].z - mu) * rstd * ln1g[col + 6] + ln1b[col + 6]);
  o[7] = f2bf((xv[1].w - mu) * rstd * ln1g[col + 7] + ln1b[col + 7]);
  *(u16x8*)&H1p[((long)(mtile * 8 + s) * 64 + lq * 16 + lr) * 8] = o;
}

// ---------------------------------------------------------------------------
// k_qkv: QKV GEMM, M=65536, N=768, K=256. 512 thr = 8 waves = 128 tokens.
// ---------------------------------------------------------------------------
__global__ __launch_bounds__(512, 4) void k_qkv(
    const unsigned short* __restrict__ H1p, unsigned short* __restrict__ QKVp,
    const unsigned short* __restrict__ wqp, const float* __restrict__ bqkv)
{
  __shared__ unsigned short buf[16384];      // 32 KB
  const int tid = threadIdx.x;
  const int wv = tid >> 6, ln = tid & 63;
  const int lr = ln & 15, lq = ln >> 4;
  const int mtile = blockIdx.x * 8 + wv;
  const f32x4 vzero = {0.f, 0.f, 0.f, 0.f};

  bf16x8 af[8];
  #pragma unroll
  for (int s = 0; s < 8; ++s)
    af[s] = *(const bf16x8*)&H1p[((long)(mtile * 8 + s) * 64 + ln) * 8];

  Stage32 st;
  stage_load(st, wqp, tid);
  for (int c = 0; c < 12; ++c) {
    stage_commit(st, buf, tid);
    __syncthreads();
    if (c < 11) stage_load(st, wqp + (c + 1) * 16384, tid);
    f32x4 acc[4];
    #pragma unroll
    for (int nt = 0; nt < 4; ++nt) acc[nt] = vzero;
    #pragma unroll
    for (int s = 0; s < 8; ++s) {
      #pragma unroll
      for (int nt = 0; nt < 4; ++nt) {
        bf16x8 b = *(const bf16x8*)&buf[(nt * 8 + s) * 512 + ln * 8];
        acc[nt] = mfma16(af[s], b, acc[nt]);
      }
    }
    #pragma unroll
    for (int nt = 0; nt < 4; ++nt) {
      const int col = c * 64 + nt * 16 + lr;
      const float bias = bqkv[col];
      #pragma unroll
      for (int reg = 0; reg < 4; ++reg) {
        const int row = mtile * 16 + lq * 4 + reg;
        QKVp[(long)row * 768 + col] = f2bf(acc[nt][reg] + bias);
      }
    }
    __syncthreads();
  }
}

// ---------------------------------------------------------------------------
// k_attn: 4 chains (32 tokens)/block; stage QKV tile, softmax-attention,
// write O in PACKED A-fragment layout for k_oproj.
// ---------------------------------------------------------------------------
#define SQV 776   // 768 + 8

__global__ __launch_bounds__(256, 3) void k_attn(
    const unsigned short* __restrict__ QKVp, const int* __restrict__ NPICK,
    unsigned short* __restrict__ Op)
{
  __shared__ unsigned short sQKV[32 * SQV];
  __shared__ int s_np[4];
  const int tid = threadIdx.x;
  const int blk = blockIdx.x;
  if (tid < 4) s_np[tid] = NPICK[blk * 4 + tid];
  for (int i = tid; i < 3072; i += 256) {
    const int r = i / 96, u = i - r * 96;
    *(u16x8*)&sQKV[r * SQV + u * 8] =
        *(const u16x8*)&QKVp[((long)blk * 32 + r) * 768 + u * 8];
  }
  __syncthreads();
  if (tid >= 128) return;

  const int c = tid >> 5, hh = (tid >> 3) & 3, qi = tid & 7;
  const int natt = max(1, s_np[c]);
  const int qrow = c * 8 + qi;
  float sc[8];
  #pragma unroll
  for (int j = 0; j < 8; ++j) sc[j] = -1e30f;
  for (int j = 0; j < natt; ++j) {
    float d = 0.f;
    #pragma unroll
    for (int dc = 0; dc < 8; ++dc) {
      bf16x8 qv = *(const bf16x8*)&sQKV[qrow * SQV + hh * 64 + dc * 8];
      bf16x8 kv = *(const bf16x8*)&sQKV[(c * 8 + j) * SQV + 256 + hh * 64 + dc * 8];
      #pragma unroll
      for (int e = 0; e < 8; ++e) d += (float)qv[e] * (float)kv[e];
    }
    sc[j] = d * 0.125f;
  }
  float mx = -1e30f;
  #pragma unroll
  for (int j = 0; j < 8; ++j) mx = fmaxf(mx, sc[j]);
  float pr[8]; float ssum = 0.f;
  #pragma unroll
  for (int j = 0; j < 8; ++j) {
    float e = (j < natt) ? __expf(sc[j] - mx) : 0.f;
    pr[j] = e; ssum += e;
  }
  const float inv = 1.f / ssum;
  const int t = blk * 32 + qrow;
  const int mt = t >> 4, lrt = t & 15;
  #pragma unroll
  for (int dc = 0; dc < 8; ++dc) {
    float o8[8] = {0.f,0.f,0.f,0.f,0.f,0.f,0.f,0.f};
    for (int j = 0; j < natt; ++j) {
      const float pj = pr[j] * inv;
      bf16x8 vv = *(const bf16x8*)&sQKV[(c * 8 + j) * SQV + 512 + hh * 64 + dc * 8];
      #pragma unroll
      for (int e = 0; e < 8; ++e) o8[e] += pj * (float)vv[e];
    }
    u16x8 o;
    #pragma unroll
    for (int e = 0; e < 8; ++e) o[e] = f2bf(o8[e]);
    const int s = hh * 2 + (dc >> 2), lqt = dc & 3;
    *(u16x8*)&Op[((long)(mt * 8 + s) * 64 + lqt * 16 + lrt) * 8] = o;
  }
}

// ---------------------------------------------------------------------------
// k_oproj: X += O @ wo^T + bo. Staged template (N=256 -> 4 chunks).
// ---------------------------------------------------------------------------
__global__ __launch_bounds__(512, 4) void k_oproj(
    const unsigned short* __restrict__ Op, float* __restrict__ X,
    const unsigned short* __restrict__ wop, const float* __restrict__ bo)
{
  __shared__ unsigned short buf[16384];
  const int tid = threadIdx.x;
  const int wv = tid >> 6, ln = tid & 63;
  const int lr = ln & 15, lq = ln >> 4;
  const int mtile = blockIdx.x * 8 + wv;
  const f32x4 vzero = {0.f, 0.f, 0.f, 0.f};

  bf16x8 af[8];
  #pragma unroll
  for (int s = 0; s < 8; ++s)
    af[s] = *(const bf16x8*)&Op[((long)(mtile * 8 + s) * 64 + ln) * 8];

  Stage32 st;
  stage_load(st, wop, tid);
  for (int c = 0; c < 4; ++c) {
    stage_commit(st, buf, tid);
    __syncthreads();
    if (c < 3) stage_load(st, wop + (c + 1) * 16384, tid);
    f32x4 acc[4];
    #pragma unroll
    for (int nt = 0; nt < 4; ++nt) acc[nt] = vzero;
    #pragma unroll
    for (int s = 0; s < 8; ++s) {
      #pragma unroll
      for (int nt = 0; nt < 4; ++nt) {
        bf16x8 b = *(const bf16x8*)&buf[(nt * 8 + s) * 512 + ln * 8];
        acc[nt] = mfma16(af[s], b, acc[nt]);
      }
    }
    #pragma unroll
    for (int nt = 0; nt < 4; ++nt) {
      const int col = c * 64 + nt * 16 + lr;
      const float bias = bo[col];
      #pragma unroll
      for (int reg = 0; reg < 4; ++reg) {
        const int row = mtile * 16 + lq * 4 + reg;
        const long gi = (long)row * DIM + col;
        X[gi] = X[gi] + acc[nt][reg] + bias;
      }
    }
    __syncthreads();
  }
}

// ---------------------------------------------------------------------------
// k_ln2: X fp32 -> H2 PACKED bf16 (64 rows/block, 4 threads/row)
// ---------------------------------------------------------------------------
__global__ __launch_bounds__(256) void k_ln2(
    const float* __restrict__ X, const float* __restrict__ g,
    const float* __restrict__ b, unsigned short* __restrict__ H2p)
{
  const int tid = threadIdx.x;
  const int row = blockIdx.x * 64 + (tid >> 2);
  const int p = tid & 3;
  const float4* xr = (const float4*)(X + (long)row * DIM + p * 64);
  float4 xv[16];
  float sum = 0.f, ss = 0.f;
  #pragma unroll
  for (int i = 0; i < 16; ++i) {
    xv[i] = xr[i];
    sum += xv[i].x + xv[i].y + xv[i].z + xv[i].w;
    ss  += xv[i].x * xv[i].x + xv[i].y * xv[i].y + xv[i].z * xv[i].z + xv[i].w * xv[i].w;
  }
  sum += __shfl_xor(sum, 1); ss += __shfl_xor(ss, 1);
  sum += __shfl_xor(sum, 2); ss += __shfl_xor(ss, 2);
  const float mu = sum * (1.f / 256.f);
  const float var = ss * (1.f / 256.f) - mu * mu;
  const float rstd = rsqrtf(var + 1e-5f);
  const int mtile = row >> 4, lr = row & 15;
  #pragma unroll
  for (int i = 0; i < 16; i += 2) {
    const int q = p * 8 + (i >> 1);
    const int s = q >> 2, lq = q & 3;
    const int col = q * 8;
    u16x8 o;
    o[0] = f2bf((xv[i].x - mu) * rstd * g[col + 0] + b[col + 0]);
    o[1] = f2bf((xv[i].y - mu) * rstd * g[col + 1] + b[col + 1]);
    o[2] = f2bf((xv[i].z - mu) * rstd * g[col + 2] + b[col + 2]);
    o[3] = f2bf((xv[i].w - mu) * rstd * g[col + 3] + b[col + 3]);
    o[4] = f2bf((xv[i+1].x - mu) * rstd * g[col + 4] + b[col + 4]);
    o[5] = f2bf((xv[i+1].y - mu) * rstd * g[col + 5] + b[col + 5]);
    o[6] = f2bf((xv[i+1].z - mu) * rstd * g[col + 6] + b[col + 6]);
    o[7] = f2bf((xv[i+1].w - mu) * rstd * g[col + 7] + b[col + 7]);
    *(u16x8*)&H2p[((long)(mtile * 8 + s) * 64 + lq * 16 + lr) * 8] = o;
  }
}

// ---------------------------------------------------------------------------
// k_ff: x += gelu(h2@wff1^T+b1)@wff2^T+b2. 512 thr = 8 waves = 128 tokens.
// ---------------------------------------------------------------------------
#define SGPAD 72    // 64+8

__global__ __launch_bounds__(512, 2) void k_ff(
    float* __restrict__ X, const unsigned short* __restrict__ H2p,
    const unsigned short* __restrict__ w1p, const unsigned short* __restrict__ w2p,
    const float* __restrict__ bff1, const float* __restrict__ bff2)
{
  __shared__ unsigned short bufA[16384];   // 32 KB: w1[f]
  __shared__ unsigned short bufB[16384];   // 32 KB: w2[f]
  __shared__ unsigned short sG[128 * SGPAD];
  const int tid = threadIdx.x;
  const int wv = tid >> 6, ln = tid & 63;
  const int lr = ln & 15, lq = ln >> 4;
  const int m0 = wv * 16;
  const int mtile = blockIdx.x * 8 + wv;
  const f32x4 vzero = {0.f, 0.f, 0.f, 0.f};

  bf16x8 af[8];
  #pragma unroll
  for (int s = 0; s < 8; ++s)
    af[s] = *(const bf16x8*)&H2p[((long)(mtile * 8 + s) * 64 + ln) * 8];

  f32x4 acc3[16];
  #pragma unroll
  for (int nt = 0; nt < 16; ++nt) acc3[nt] = vzero;

  Stage32 stA, stB;
  stage_load(stA, w1p, tid);
  stage_load(stB, w2p, tid);

  for (int f = 0; f < 16; ++f) {
    stage_commit(stA, bufA, tid);
    stage_commit(stB, bufB, tid);
    __syncthreads();
    if (f < 15) {
      stage_load(stA, w1p + (f + 1) * 16384, tid);
      stage_load(stB, w2p + (f + 1) * 16384, tid);
    }
    f32x4 ga[4];
    #pragma unroll
    for (int nt = 0; nt < 4; ++nt) ga[nt] = vzero;
    #pragma unroll
    for (int s = 0; s < 8; ++s) {
      #pragma unroll
      for (int nt = 0; nt < 4; ++nt) {
        bf16x8 b = *(const bf16x8*)&bufA[(nt * 8 + s) * 512 + ln * 8];
        ga[nt] = mfma16(af[s], b, ga[nt]);
      }
    }
    #pragma unroll
    for (int nt = 0; nt < 4; ++nt) {
      const int n = f * 64 + nt * 16 + lr;
      const float bias = bff1[n];
      #pragma unroll
      for (int reg = 0; reg < 4; ++reg) {
        sG[(m0 + lq * 4 + reg) * SGPAD + nt * 16 + lr] = f2bf(gelu_exact(ga[nt][reg] + bias));
      }
    }
    // wave-private sG rows: no barrier between FF1 and FF2
    #pragma unroll
    for (int s2 = 0; s2 < 2; ++s2) {
      bf16x8 ag = *(const bf16x8*)&sG[(m0 + lr) * SGPAD + s2 * 32 + lq * 8];
      #pragma unroll
      for (int nt = 0; nt < 16; ++nt) {
        bf16x8 b = *(const bf16x8*)&bufB[(s2 * 16 + nt) * 512 + ln * 8];
        acc3[nt] = mfma16(ag, b, acc3[nt]);
      }
    }
    __syncthreads();
  }
  #pragma unroll
  for (int nt = 0; nt < 16; ++nt) {
    const int col = nt * 16 + lr;
    const float bias = bff2[col];
    #pragma unroll
    for (int reg = 0; reg < 4; ++reg) {
      const int row = mtile * 16 + lq * 4 + reg;
      const long gi = (long)row * DIM + col;
      X[gi] = X[gi] + acc3[nt][reg] + bias;
    }
  }
}

// ---------------------------------------------------------------------------
// k_pool: masked mean pool + log1p(count) -> F PACKED bf16 [8192 x 320].
// 256 blocks x 32 chains (8 threads/chain).
// ---------------------------------------------------------------------------
__global__ __launch_bounds__(256) void k_pool(
    const float* __restrict__ X, const int* __restrict__ NPICK,
    const float* __restrict__ count, unsigned short* __restrict__ Fp)
{
  const int tid = threadIdx.x;
  const int cc = tid >> 3, p = tid & 7;
  const int chain = blockIdx.x * 32 + cc;
  const int np = NPICK[chain];
  const float inv = (np > 0) ? (1.f / (float)np) : 0.f;
  const int rtile = chain >> 4, lr = chain & 15;
  const float4* xb = (const float4*)(X + (long)chain * KTOK * DIM);
  #pragma unroll
  for (int i = 0; i < 8; i += 2) {
    float4 s0 = make_float4(0.f, 0.f, 0.f, 0.f);
    float4 s1 = make_float4(0.f, 0.f, 0.f, 0.f);
    for (int j = 0; j < np; ++j) {
      float4 t0 = xb[j * 64 + p * 8 + i];
      float4 t1 = xb[j * 64 + p * 8 + i + 1];
      s0.x += t0.x; s0.y += t0.y; s0.z += t0.z; s0.w += t0.w;
      s1.x += t1.x; s1.y += t1.y; s1.z += t1.z; s1.w += t1.w;
    }
    const int q = p * 4 + (i >> 1);
    const int s = q >> 2, lq = q & 3;
    u16x8 o;
    o[0] = f2bf(s0.x * inv); o[1] = f2bf(s0.y * inv);
    o[2] = f2bf(s0.z * inv); o[3] = f2bf(s0.w * inv);
    o[4] = f2bf(s1.x * inv); o[5] = f2bf(s1.y * inv);
    o[6] = f2bf(s1.z * inv); o[7] = f2bf(s1.w * inv);
    *(u16x8*)&Fp[((long)(rtile * 10 + s) * 64 + lq * 16 + lr) * 8] = o;
  }
  if (p == 7) {
    #pragma unroll
    for (int q = 32; q < 40; ++q) {
      const int s = q >> 2, lq = q & 3;
      u16x8 o = {0,0,0,0,0,0,0,0};
      if (q == 32) o[0] = f2bf(log1pf(count[chain]));
      *(u16x8*)&Fp[((long)(rtile * 10 + s) * 64 + lq * 16 + lr) * 8] = o;
    }
  }
}

// ---------------------------------------------------------------------------
// k_headmlp: out += partial over FF-quarter of gelu(F@wout1^T+b1)@wout2^T
// (+ bout2 from quarter 0). 512 thr = 8 waves = 128 chains; grid 64 m-chunks
// x 4 FF-quarters = 256 blocks. Weights staged per f-chunk: w1 40KB + w2 32KB.
// out must be pre-zeroed (hipMemsetAsync); fp32 atomicAdd accumulation.
// ---------------------------------------------------------------------------
__global__ __launch_bounds__(512, 2) void k_headmlp(
    const unsigned short* __restrict__ Fp,
    const unsigned short* __restrict__ wo1p, const unsigned short* __restrict__ wo2p,
    const float* __restrict__ bout1, const float* __restrict__ bout2,
    float* __restrict__ out)
{
  __shared__ unsigned short bufA[20480];   // 40 KB: wout1 f-chunk (40 groups)
  __shared__ unsigned short bufB[16384];   // 32 KB: wout2 f-chunk (32 groups)
  __shared__ unsigned short sG[128 * SGPAD];
  const int tid = threadIdx.x;
  const int fq = blockIdx.x & 3;           // FF-quarter
  const int mchunk = blockIdx.x >> 2;      // 0..63 (128 chains each)
  const int wv = tid >> 6, ln = tid & 63;
  const int lr = ln & 15, lq = ln >> 4;
  const int m0 = wv * 16;
  const int rtile = mchunk * 8 + wv;
  const f32x4 vzero = {0.f, 0.f, 0.f, 0.f};

  bf16x8 af[10];
  #pragma unroll
  for (int s = 0; s < 10; ++s)
    af[s] = *(const bf16x8*)&Fp[((long)(rtile * 10 + s) * 64 + ln) * 8];

  f32x4 oacc[16];
  #pragma unroll
  for (int nt = 0; nt < 16; ++nt) oacc[nt] = vzero;

  // stage regs: w1 chunk = 2560 u16x8 (5/thread), w2 chunk = 2048 (4/thread)
  u16x8 rA[5]; u16x8 rB[4];
  {
    const unsigned short* a0 = wo1p + (fq * 4) * 20480;
    const unsigned short* b0 = wo2p + (fq * 4) * 16384;
    #pragma unroll
    for (int i = 0; i < 5; ++i) rA[i] = *(const u16x8*)&a0[(tid + i * 512) * 8];
    #pragma unroll
    for (int i = 0; i < 4; ++i) rB[i] = *(const u16x8*)&b0[(tid + i * 512) * 8];
  }

  for (int it = 0; it < 4; ++it) {
    const int f = fq * 4 + it;
    #pragma unroll
    for (int i = 0; i < 5; ++i) *(u16x8*)&bufA[(tid + i * 512) * 8] = rA[i];
    #pragma unroll
    for (int i = 0; i < 4; ++i) *(u16x8*)&bufB[(tid + i * 512) * 8] = rB[i];
    __syncthreads();
    if (it < 3) {
      const unsigned short* a0 = wo1p + (f + 1) * 20480;
      const unsigned short* b0 = wo2p + (f + 1) * 16384;
      #pragma unroll
      for (int i = 0; i < 5; ++i) rA[i] = *(const u16x8*)&a0[(tid + i * 512) * 8];
      #pragma unroll
      for (int i = 0; i < 4; ++i) rB[i] = *(const u16x8*)&b0[(tid + i * 512) * 8];
    }
    // out1: 64 FF-cols, K=320
    f32x4 ga[4];
    #pragma unroll
    for (int nt = 0; nt < 4; ++nt) ga[nt] = vzero;
    #pragma unroll
    for (int s = 0; s < 10; ++s) {
      #pragma unroll
      for (int nt = 0; nt < 4; ++nt) {
        bf16x8 b = *(const bf16x8*)&bufA[(nt * 10 + s) * 512 + ln * 8];
        ga[nt] = mfma16(af[s], b, ga[nt]);
      }
    }
    #pragma unroll
    for (int nt = 0; nt < 4; ++nt) {
      const int n = f * 64 + nt * 16 + lr;
      const float bias = bout1[n];
      #pragma unroll
      for (int reg = 0; reg < 4; ++reg) {
        sG[(m0 + lq * 4 + reg) * SGPAD + nt * 16 + lr] = f2bf(gelu_exact(ga[nt][reg] + bias));
      }
    }
    // out2 partial (wave-private sG, no barrier)
    #pragma unroll
    for (int s2 = 0; s2 < 2; ++s2) {
      bf16x8 ag = *(const bf16x8*)&sG[(m0 + lr) * SGPAD + s2 * 32 + lq * 8];
      #pragma unroll
      for (int nt = 0; nt < 16; ++nt) {
        bf16x8 b = *(const bf16x8*)&bufB[(s2 * 16 + nt) * 512 + ln * 8];
        oacc[nt] = mfma16(ag, b, oacc[nt]);
      }
    }
    __syncthreads();
  }
  #pragma unroll
  for (int nt = 0; nt < 16; ++nt) {
    const int col = nt * 16 + lr;
    const float bias = (fq == 0) ? bout2[col] : 0.f;
    #pragma unroll
    for (int reg = 0; reg < 4; ++reg) {
      const int row = mchunk * 128 + m0 + lq * 4 + reg;
      atomicAdd(&out[(long)row * DIM + col], oacc[nt][reg] + bias);
    }
  }
}

// ---------------------------------------------------------------------------
extern "C" void kernel_launch(void* const* d_in, const int* in_sizes, int n_in,
                              void* d_out, int out_size, void* d_ws, size_t ws_size,
                              hipStream_t stream) {
  (void)in_sizes; (void)n_in; (void)out_size; (void)ws_size;
  const float* v          = (const float*)d_in[0];
  const int*   batch_idx  = (const int*)  d_in[1];
  const int*   mask       = (const int*)  d_in[2];
  const float* count      = (const float*)d_in[3];
  const float* rank       = (const float*)d_in[4];
  const float* pe         = (const float*)d_in[5];
  const float* w_qkv      = (const float*)d_in[6];
  const float* b_qkv      = (const float*)d_in[7];
  const float* w_o        = (const float*)d_in[8];
  const float* b_o        = (const float*)d_in[9];
  const float* ln1g       = (const float*)d_in[10];
  const float* ln1b       = (const float*)d_in[11];
  const float* ln2g       = (const float*)d_in[12];
  const float* ln2b       = (const float*)d_in[13];
  const float* w_ff1      = (const float*)d_in[14];
  const float* b_ff1      = (const float*)d_in[15];
  const float* w_ff2      = (const float*)d_in[16];
  const float* b_ff2      = (const float*)d_in[17];
  const float* w_out1     = (const float*)d_in[18];
  const float* b_out1     = (const float*)d_in[19];
  const float* w_out2     = (const float*)d_in[20];
  const float* b_out2     = (const float*)d_in[21];
  float* out = (float*)d_out;

  char* ws = (char*)d_ws;
  float*          X     = (float*)ws;                              // 67,108,864
  unsigned short* H1p   = (unsigned short*)(ws + 67108864);        // 33,554,432
  unsigned short* Op    = H1p;                                     // alias: H1p dead after k_qkv
  unsigned short* QKVp  = (unsigned short*)(ws + 100663296);       // 100,663,296 (65536x768 bf16)
  unsigned short* H2p   = QKVp;                                    // alias: QKVp dead after k_attn
  unsigned short* Fp    = (unsigned short*)(ws + 134217728);       // alias inside QKVp region
  int*            NPICK = (int*)(ws + 201326592);                  //     32,768
  unsigned short* wq_bf   = (unsigned short*)(ws + 201359360);     //    393,216
  unsigned short* wo_bf   = (unsigned short*)(ws + 201752576);     //    131,072
  unsigned short* wff1_bf = (unsigned short*)(ws + 201883648);     //    524,288
  unsigned short* wff2_bf = (unsigned short*)(ws + 202407936);     //    524,288 (k-major)
  unsigned short* wo1_bf  = (unsigned short*)(ws + 202932224);     //    655,360 (n-major, f-chunked)
  unsigned short* wo2_bf  = (unsigned short*)(ws + 203587584);     //    524,288 (k-major) -> end 204,111,872

  k_prep<<<PREP_GROUPS / 256, 256, 0, stream>>>(
      w_qkv, w_o, w_ff1, w_ff2, w_out1, w_out2,
      wq_bf, wo_bf, wff1_bf, wff2_bf, wo1_bf, wo2_bf);

  k_sel<<<8192, 256, 0, stream>>>(v, batch_idx, mask, rank, pe,
                                  ln1g, ln1b, X, H1p, NPICK);

  k_qkv<<<512, 512, 0, stream>>>(H1p, QKVp, wq_bf, b_qkv);

  k_attn<<<2048, 256, 0, stream>>>(QKVp, NPICK, Op);

  k_oproj<<<512, 512, 0, stream>>>(Op, X, wo_bf, b_o);

  k_ln2<<<1024, 256, 0, stream>>>(X, ln2g, ln2b, H2p);

  k_ff<<<512, 512, 0, stream>>>(X, H2p, wff1_bf, wff2_bf, b_ff1, b_ff2);

  k_pool<<<256, 256, 0, stream>>>(X, NPICK, count, Fp);

  hipMemsetAsync(out, 0, (size_t)8192 * 256 * sizeof(float), stream);

  k_headmlp<<<256, 512, 0, stream>>>(Fp, wo1_bf, wo2_bf, b_out1, b_out2, out);
}

// Round 6
// 589.398 us; speedup vs baseline: 2.5864x; 1.0759x over previous
//
#include <hip/hip_runtime.h>

// ============================================================================
// TransformerSubsetAggregator on MI355X (gfx950) — round 6
// vs r5: (1) gelu via tanh-form (v_exp+v_rcp, ~12 VALU ops) replacing erff
// (~90 ops w/ divergence) — k_ff was VALU-bound on gelu (VALUBusy 46%).
// (2) k_qkv/k_oproj: per-wave LDS transpose of D-fragments -> coalesced
// 16B/lane global stores (were 2B/4B scattered scalar stores).
// Pipeline: k_prep | k_sel(+LN1->H1p) | k_qkv | k_attn | k_oproj | k_ln2 |
//           k_ff | k_pool | memset(out) | k_headmlp
// ============================================================================

#define DIM   256
#define LSEQ  128
#define KTOK  8

typedef __bf16 bf16x8 __attribute__((ext_vector_type(8)));
typedef float  f32x4  __attribute__((ext_vector_type(4)));
typedef unsigned short u16x8 __attribute__((ext_vector_type(8)));

__device__ __forceinline__ f32x4 mfma16(bf16x8 a, bf16x8 b, f32x4 c) {
  // A/B frag: m(or n)=lane&15, k=(lane>>4)*8+j ; D: col=lane&15, row=(lane>>4)*4+reg
  return __builtin_amdgcn_mfma_f32_16x16x32_bf16(a, b, c, 0, 0, 0);
}

__device__ __forceinline__ unsigned short f2bf(float f) {
  unsigned u = __float_as_uint(f);
  u = (u + 0x7FFFu + ((u >> 16) & 1u)) >> 16;   // RNE
  return (unsigned short)u;
}

// tanh-form gelu: max dev from exact ~1e-3, below the bf16 rounding (~8e-3)
// applied to these values anyway. ~12 VALU ops vs ~90 for branchy erff.
__device__ __forceinline__ float gelu_fast(float x) {
  const float y = 0.7978845608f * __builtin_fmaf(0.044715f * x * x, x, x);
  const float e = __expf(2.f * y);
  const float t = 1.f - 2.f * __builtin_amdgcn_rcpf(e + 1.f);
  return 0.5f * x * (1.f + t);
}

// ---- 32KB chunk staging: register prefetch + LDS commit (512-thread blocks)
struct Stage32 { u16x8 r[4]; };
__device__ __forceinline__ void stage_load(Stage32& st, const unsigned short* __restrict__ g, int tid) {
  #pragma unroll
  for (int i = 0; i < 4; ++i) st.r[i] = *(const u16x8*)&g[(tid + i * 512) * 8];
}
__device__ __forceinline__ void stage_commit(const Stage32& st, unsigned short* l, int tid) {
  #pragma unroll
  for (int i = 0; i < 4; ++i) *(u16x8*)&l[(tid + i * 512) * 8] = st.r[i];
}

// ---------------------------------------------------------------------------
// k_prep: pack weights fp32 -> bf16 fragment-major.
// n-major (KC): group (ntile*KC + s); k-major (NT): group (s*NT + ntile).
// ---------------------------------------------------------------------------
__device__ __forceinline__ void pack_region(
    const float* __restrict__ src, unsigned short* __restrict__ dst,
    int g, int KC, int Ksrc, int Klim)
{
  const int ln = g & 63;
  const int t = g >> 6;
  const int s = t % KC;
  const int ntile = t / KC;
  const int row = ntile * 16 + (ln & 15);
  const int c0 = s * 32 + (ln >> 4) * 8;
  u16x8 o;
  #pragma unroll
  for (int j = 0; j < 8; ++j) {
    float val = (c0 + j < Klim) ? src[(long)row * Ksrc + c0 + j] : 0.f;
    o[j] = f2bf(val);
  }
  *(u16x8*)&dst[(long)g * 8] = o;
}

__device__ __forceinline__ void pack_region_kmaj(
    const float* __restrict__ src, unsigned short* __restrict__ dst,
    int g, int NT, int Ksrc)
{
  const int ln = g & 63;
  const int t = g >> 6;
  const int ntile = t % NT;
  const int s = t / NT;
  const int row = ntile * 16 + (ln & 15);
  const int c0 = s * 32 + (ln >> 4) * 8;
  u16x8 o;
  #pragma unroll
  for (int j = 0; j < 8; ++j) o[j] = f2bf(src[(long)row * Ksrc + c0 + j]);
  *(u16x8*)&dst[(long)g * 8] = o;
}

#define PREP_GROUPS 172032
__global__ __launch_bounds__(256) void k_prep(
    const float* __restrict__ wqkv, const float* __restrict__ wo,
    const float* __restrict__ wff1, const float* __restrict__ wff2,
    const float* __restrict__ wout1, const float* __restrict__ wout2,
    unsigned short* __restrict__ oq, unsigned short* __restrict__ oo,
    unsigned short* __restrict__ of1, unsigned short* __restrict__ of2,
    unsigned short* __restrict__ oo1, unsigned short* __restrict__ oo2)
{
  int g = blockIdx.x * 256 + threadIdx.x;
  if (g < 24576) { pack_region(wqkv, oq, g, 8, 256, 256); return; }     // n-major
  g -= 24576;
  if (g < 8192)  { pack_region(wo, oo, g, 8, 256, 256); return; }       // n-major
  g -= 8192;
  if (g < 32768) { pack_region(wff1, of1, g, 8, 256, 256); return; }    // n-major (f-chunked)
  g -= 32768;
  if (g < 32768) { pack_region_kmaj(wff2, of2, g, 16, 1024); return; }  // k-major
  g -= 32768;
  if (g < 40960) { pack_region(wout1, oo1, g, 10, 257, 257); return; }  // n-major (f-chunked)
  g -= 40960;
  if (g < 32768) { pack_region_kmaj(wout2, oo2, g, 16, 1024); }         // k-major
}

// ---------------------------------------------------------------------------
// k_sel: top-8 (lax.top_k ties: value desc, idx asc), sort picked idx asc,
// gather v + pos_embed -> X fp32 (row-major), fused LN1 -> H1 PACKED bf16.
// ---------------------------------------------------------------------------
__global__ __launch_bounds__(256) void k_sel(
    const float* __restrict__ v, const int* __restrict__ batch_idx,
    const int* __restrict__ mask, const float* __restrict__ rank_scores,
    const float* __restrict__ pos_embed,
    const float* __restrict__ ln1g, const float* __restrict__ ln1b,
    float* __restrict__ X, unsigned short* __restrict__ H1p,
    int* __restrict__ NPICK)
{
  const int c = blockIdx.x;
  const int tid = threadIdx.x;
  __shared__ int s_mem[KTOK];
  __shared__ int s_np;

  if (tid < 64) {
    const int l = tid;
    unsigned long long key[2];
    #pragma unroll
    for (int t = 0; t < 2; ++t) {
      int p = l + 64 * t;
      int mk = mask[c * LSEQ + p];
      float s = rank_scores[c * LSEQ + p];
      unsigned u = __float_as_uint(s);
      u = (u & 0x80000000u) ? ~u : (u | 0x80000000u);
      unsigned long long kk =
          ((unsigned long long)u << 32) | (unsigned long long)(0xFFFFFFFFu - (unsigned)p);
      key[t] = mk ? kk : 0ull;
    }
    int w[KTOK];
    #pragma unroll
    for (int r = 0; r < KTOK; ++r) w[r] = 0x7FFFFFFF;
    int np = 0;
    for (int r = 0; r < KTOK; ++r) {
      unsigned long long best = key[0] > key[1] ? key[0] : key[1];
      for (int off = 32; off > 0; off >>= 1) {
        unsigned long long o = __shfl_xor(best, off, 64);
        if (o > best) best = o;
      }
      if (best == 0ull) break;
      int idx = (int)(0xFFFFFFFFu - (unsigned)(best & 0xFFFFFFFFull));
      w[np++] = idx;
      if (key[0] == best) key[0] = 0ull;
      if (key[1] == best) key[1] = 0ull;
    }
    #pragma unroll
    for (int a = 0; a < KTOK - 1; ++a)
      #pragma unroll
      for (int b2 = 0; b2 < KTOK - 1 - a; ++b2) {
        int x0 = w[b2], x1 = w[b2 + 1];
        w[b2] = min(x0, x1); w[b2 + 1] = max(x0, x1);
      }
    if (l < KTOK) s_mem[l] = (l < np) ? batch_idx[c * LSEQ + w[l]] : -1;
    if (l == 0) { s_np = np; NPICK[c] = np; }
  }
  __syncthreads();

  const int np = s_np;
  const int j = tid >> 5, q = tid & 31;     // 32 threads/token, 8 cols each
  const int r = s_mem[j];
  const float4* v4  = (const float4*)v;
  const float4* pe4 = (const float4*)pos_embed;
  float4* X4 = (float4*)X;

  float4 xv[2];                              // cols q*8 .. q*8+7
  #pragma unroll
  for (int rep = 0; rep < 2; ++rep) {
    const int f = 2 * q + rep;
    float4 pe = pe4[j * 64 + f];
    float4 val = make_float4(0.f, 0.f, 0.f, 0.f);
    if (j < np) val = v4[(long)r * 64 + f];
    xv[rep].x = val.x + pe.x; xv[rep].y = val.y + pe.y;
    xv[rep].z = val.z + pe.z; xv[rep].w = val.w + pe.w;
    X4[((long)c * KTOK + j) * 64 + f] = xv[rep];
  }
  float sum = 0.f, ss = 0.f;
  #pragma unroll
  for (int rep = 0; rep < 2; ++rep) {
    sum += xv[rep].x + xv[rep].y + xv[rep].z + xv[rep].w;
    ss  += xv[rep].x * xv[rep].x + xv[rep].y * xv[rep].y
         + xv[rep].z * xv[rep].z + xv[rep].w * xv[rep].w;
  }
  #pragma unroll
  for (int off = 1; off <= 16; off <<= 1) {
    sum += __shfl_xor(sum, off); ss += __shfl_xor(ss, off);
  }
  const float mu = sum * (1.f / 256.f);
  const float var = ss * (1.f / 256.f) - mu * mu;
  const float rstd = rsqrtf(var + 1e-5f);
  const int t = c * KTOK + j;
  const int mtile = t >> 4, lr = t & 15;
  const int s = q >> 2, lq = q & 3;
  u16x8 o;
  const int col = q * 8;
  o[0] = f2bf((xv[0].x - mu) * rstd * ln1g[col + 0] + ln1b[col + 0]);
  o[1] = f2bf((xv[0].y - mu) * rstd * ln1g[col + 1] + ln1b[col + 1]);
  o[2] = f2bf((xv[0].z - mu) * rstd * ln1g[col + 2] + ln1b[col + 2]);
  o[3] = f2bf((xv[0].w - mu) * rstd * ln1g[col + 3] + ln1b[col + 3]);
  o[4] = f2bf((xv[1].x - mu) * rstd * ln1g[col + 4] + ln1b[col + 4]);
  o[5] = f2bf((xv[1].y - mu) * rstd * ln1g[col + 5] + ln1b[col + 5]);
  o[6] = f2bf((xv[1].z - mu) * rstd * ln1g[col + 6] + ln1b[col + 6]);
  o[7] = f2bf((xv[1].w - mu) * rstd * ln1g[col + 7] + ln1b[col + 7]);
  *(u16x8*)&H1p[((long)(mtile * 8 + s) * 64 + lq * 16 + lr) * 8] = o;
}

// ---------------------------------------------------------------------------
// k_qkv: QKV GEMM, M=65536, N=768, K=256. 512 thr = 8 waves = 128 tokens.
// D-frag -> per-wave LDS transpose -> coalesced 16B/lane row-major stores.
// LDS 32K buf + 18K sT = 50.4KB -> 3 blocks/CU.
// ---------------------------------------------------------------------------
__global__ __launch_bounds__(512, 4) void k_qkv(
    const unsigned short* __restrict__ H1p, unsigned short* __restrict__ QKVp,
    const unsigned short* __restrict__ wqp, const float* __restrict__ bqkv)
{
  __shared__ unsigned short buf[16384];      // 32 KB
  __shared__ unsigned short sT[8 * 16 * 72]; // per-wave 16 tok x 64 col (+8 pad)
  const int tid = threadIdx.x;
  const int wv = tid >> 6, ln = tid & 63;
  const int lr = ln & 15, lq = ln >> 4;
  const int mtile = blockIdx.x * 8 + wv;
  const f32x4 vzero = {0.f, 0.f, 0.f, 0.f};
  unsigned short* sTw = &sT[wv * 1152];

  bf16x8 af[8];
  #pragma unroll
  for (int s = 0; s < 8; ++s)
    af[s] = *(const bf16x8*)&H1p[((long)(mtile * 8 + s) * 64 + ln) * 8];

  Stage32 st;
  stage_load(st, wqp, tid);
  for (int c = 0; c < 12; ++c) {
    stage_commit(st, buf, tid);
    __syncthreads();
    if (c < 11) stage_load(st, wqp + (c + 1) * 16384, tid);
    f32x4 acc[4];
    #pragma unroll
    for (int nt = 0; nt < 4; ++nt) acc[nt] = vzero;
    #pragma unroll
    for (int s = 0; s < 8; ++s) {
      #pragma unroll
      for (int nt = 0; nt < 4; ++nt) {
        bf16x8 b = *(const bf16x8*)&buf[(nt * 8 + s) * 512 + ln * 8];
        acc[nt] = mfma16(af[s], b, acc[nt]);
      }
    }
    // per-wave transpose (cross-lane within wave; lgkmcnt handles RAW)
    #pragma unroll
    for (int nt = 0; nt < 4; ++nt) {
      const float bias = bqkv[c * 64 + nt * 16 + lr];
      #pragma unroll
      for (int reg = 0; reg < 4; ++reg)
        sTw[(lq * 4 + reg) * 72 + nt * 16 + lr] = f2bf(acc[nt][reg] + bias);
    }
    const int r8 = ln >> 3, cg = ln & 7;
    #pragma unroll
    for (int h = 0; h < 2; ++h) {
      const int tok = h * 8 + r8;
      u16x8 vv = *(const u16x8*)&sTw[tok * 72 + cg * 8];
      *(u16x8*)&QKVp[((long)(mtile * 16 + tok)) * 768 + c * 64 + cg * 8] = vv;
    }
    __syncthreads();
  }
}

// ---------------------------------------------------------------------------
// k_attn: 4 chains (32 tokens)/block; stage QKV tile, softmax-attention,
// write O in PACKED A-fragment layout for k_oproj.
// ---------------------------------------------------------------------------
#define SQV 776   // 768 + 8

__global__ __launch_bounds__(256, 3) void k_attn(
    const unsigned short* __restrict__ QKVp, const int* __restrict__ NPICK,
    unsigned short* __restrict__ Op)
{
  __shared__ unsigned short sQKV[32 * SQV];
  __shared__ int s_np[4];
  const int tid = threadIdx.x;
  const int blk = blockIdx.x;
  if (tid < 4) s_np[tid] = NPICK[blk * 4 + tid];
  for (int i = tid; i < 3072; i += 256) {
    const int r = i / 96, u = i - r * 96;
    *(u16x8*)&sQKV[r * SQV + u * 8] =
        *(const u16x8*)&QKVp[((long)blk * 32 + r) * 768 + u * 8];
  }
  __syncthreads();
  if (tid >= 128) return;

  const int c = tid >> 5, hh = (tid >> 3) & 3, qi = tid & 7;
  const int natt = max(1, s_np[c]);
  const int qrow = c * 8 + qi;
  float sc[8];
  #pragma unroll
  for (int j = 0; j < 8; ++j) sc[j] = -1e30f;
  for (int j = 0; j < natt; ++j) {
    float d = 0.f;
    #pragma unroll
    for (int dc = 0; dc < 8; ++dc) {
      bf16x8 qv = *(const bf16x8*)&sQKV[qrow * SQV + hh * 64 + dc * 8];
      bf16x8 kv = *(const bf16x8*)&sQKV[(c * 8 + j) * SQV + 256 + hh * 64 + dc * 8];
      #pragma unroll
      for (int e = 0; e < 8; ++e) d += (float)qv[e] * (float)kv[e];
    }
    sc[j] = d * 0.125f;
  }
  float mx = -1e30f;
  #pragma unroll
  for (int j = 0; j < 8; ++j) mx = fmaxf(mx, sc[j]);
  float pr[8]; float ssum = 0.f;
  #pragma unroll
  for (int j = 0; j < 8; ++j) {
    float e = (j < natt) ? __expf(sc[j] - mx) : 0.f;
    pr[j] = e; ssum += e;
  }
  const float inv = 1.f / ssum;
  const int t = blk * 32 + qrow;
  const int mt = t >> 4, lrt = t & 15;
  #pragma unroll
  for (int dc = 0; dc < 8; ++dc) {
    float o8[8] = {0.f,0.f,0.f,0.f,0.f,0.f,0.f,0.f};
    for (int j = 0; j < natt; ++j) {
      const float pj = pr[j] * inv;
      bf16x8 vv = *(const bf16x8*)&sQKV[(c * 8 + j) * SQV + 512 + hh * 64 + dc * 8];
      #pragma unroll
      for (int e = 0; e < 8; ++e) o8[e] += pj * (float)vv[e];
    }
    u16x8 o;
    #pragma unroll
    for (int e = 0; e < 8; ++e) o[e] = f2bf(o8[e]);
    const int s = hh * 2 + (dc >> 2), lqt = dc & 3;
    *(u16x8*)&Op[((long)(mt * 8 + s) * 64 + lqt * 16 + lrt) * 8] = o;
  }
}

// ---------------------------------------------------------------------------
// k_oproj: X += O @ wo^T + bo. Staged weights; per-wave fp32 LDS transpose
// -> coalesced float4 RMW on X. LDS 32K + 34.8K = 66.8KB -> 2 blocks/CU.
// ---------------------------------------------------------------------------
__global__ __launch_bounds__(512, 4) void k_oproj(
    const unsigned short* __restrict__ Op, float* __restrict__ X,
    const unsigned short* __restrict__ wop, const float* __restrict__ bo)
{
  __shared__ unsigned short buf[16384];
  __shared__ float sTf[8 * 16 * 68];         // per-wave 16 tok x 64 col (+4 pad)
  const int tid = threadIdx.x;
  const int wv = tid >> 6, ln = tid & 63;
  const int lr = ln & 15, lq = ln >> 4;
  const int mtile = blockIdx.x * 8 + wv;
  const f32x4 vzero = {0.f, 0.f, 0.f, 0.f};
  float* sTw = &sTf[wv * 1088];

  bf16x8 af[8];
  #pragma unroll
  for (int s = 0; s < 8; ++s)
    af[s] = *(const bf16x8*)&Op[((long)(mtile * 8 + s) * 64 + ln) * 8];

  Stage32 st;
  stage_load(st, wop, tid);
  for (int c = 0; c < 4; ++c) {
    stage_commit(st, buf, tid);
    __syncthreads();
    if (c < 3) stage_load(st, wop + (c + 1) * 16384, tid);
    f32x4 acc[4];
    #pragma unroll
    for (int nt = 0; nt < 4; ++nt) acc[nt] = vzero;
    #pragma unroll
    for (int s = 0; s < 8; ++s) {
      #pragma unroll
      for (int nt = 0; nt < 4; ++nt) {
        bf16x8 b = *(const bf16x8*)&buf[(nt * 8 + s) * 512 + ln * 8];
        acc[nt] = mfma16(af[s], b, acc[nt]);
      }
    }
    #pragma unroll
    for (int nt = 0; nt < 4; ++nt) {
      const float bias = bo[c * 64 + nt * 16 + lr];
      #pragma unroll
      for (int reg = 0; reg < 4; ++reg)
        sTw[(lq * 4 + reg) * 68 + nt * 16 + lr] = acc[nt][reg] + bias;
    }
    const int r4 = ln >> 2, g4 = ln & 3;
    #pragma unroll
    for (int it = 0; it < 4; ++it) {
      const int gi = it * 4 + g4;
      f32x4 vv = *(const f32x4*)&sTw[r4 * 68 + gi * 4];
      float4* xp = (float4*)&X[((long)(mtile * 16 + r4)) * DIM + c * 64 + gi * 4];
      float4 old = *xp;
      old.x += vv[0]; old.y += vv[1]; old.z += vv[2]; old.w += vv[3];
      *xp = old;
    }
    __syncthreads();
  }
}

// ---------------------------------------------------------------------------
// k_ln2: X fp32 -> H2 PACKED bf16 (64 rows/block, 4 threads/row)
// ---------------------------------------------------------------------------
__global__ __launch_bounds__(256) void k_ln2(
    const float* __restrict__ X, const float* __restrict__ g,
    const float* __restrict__ b, unsigned short* __restrict__ H2p)
{
  const int tid = threadIdx.x;
  const int row = blockIdx.x * 64 + (tid >> 2);
  const int p = tid & 3;
  const float4* xr = (const float4*)(X + (long)row * DIM + p * 64);
  float4 xv[16];
  float sum = 0.f, ss = 0.f;
  #pragma unroll
  for (int i = 0; i < 16; ++i) {
    xv[i] = xr[i];
    sum += xv[i].x + xv[i].y + xv[i].z + xv[i].w;
    ss  += xv[i].x * xv[i].x + xv[i].y * xv[i].y + xv[i].z * xv[i].z + xv[i].w * xv[i].w;
  }
  sum += __shfl_xor(sum, 1); ss += __shfl_xor(ss, 1);
  sum += __shfl_xor(sum, 2); ss += __shfl_xor(ss, 2);
  const float mu = sum * (1.f / 256.f);
  const float var = ss * (1.f / 256.f) - mu * mu;
  const float rstd = rsqrtf(var + 1e-5f);
  const int mtile = row >> 4, lr = row & 15;
  #pragma unroll
  for (int i = 0; i < 16; i += 2) {
    const int q = p * 8 + (i >> 1);
    const int s = q >> 2, lq = q & 3;
    const int col = q * 8;
    u16x8 o;
    o[0] = f2bf((xv[i].x - mu) * rstd * g[col + 0] + b[col + 0]);
    o[1] = f2bf((xv[i].y - mu) * rstd * g[col + 1] + b[col + 1]);
    o[2] = f2bf((xv[i].z - mu) * rstd * g[col + 2] + b[col + 2]);
    o[3] = f2bf((xv[i].w - mu) * rstd * g[col + 3] + b[col + 3]);
    o[4] = f2bf((xv[i+1].x - mu) * rstd * g[col + 4] + b[col + 4]);
    o[5] = f2bf((xv[i+1].y - mu) * rstd * g[col + 5] + b[col + 5]);
    o[6] = f2bf((xv[i+1].z - mu) * rstd * g[col + 6] + b[col + 6]);
    o[7] = f2bf((xv[i+1].w - mu) * rstd * g[col + 7] + b[col + 7]);
    *(u16x8*)&H2p[((long)(mtile * 8 + s) * 64 + lq * 16 + lr) * 8] = o;
  }
}

// ---------------------------------------------------------------------------
// k_ff: x += gelu(h2@wff1^T+b1)@wff2^T+b2. 512 thr = 8 waves = 128 tokens.
// ---------------------------------------------------------------------------
#define SGPAD 72    // 64+8

__global__ __launch_bounds__(512, 2) void k_ff(
    float* __restrict__ X, const unsigned short* __restrict__ H2p,
    const unsigned short* __restrict__ w1p, const unsigned short* __restrict__ w2p,
    const float* __restrict__ bff1, const float* __restrict__ bff2)
{
  __shared__ unsigned short bufA[16384];   // 32 KB: w1[f]
  __shared__ unsigned short bufB[16384];   // 32 KB: w2[f]
  __shared__ unsigned short sG[128 * SGPAD];
  const int tid = threadIdx.x;
  const int wv = tid >> 6, ln = tid & 63;
  const int lr = ln & 15, lq = ln >> 4;
  const int m0 = wv * 16;
  const int mtile = blockIdx.x * 8 + wv;
  const f32x4 vzero = {0.f, 0.f, 0.f, 0.f};

  bf16x8 af[8];
  #pragma unroll
  for (int s = 0; s < 8; ++s)
    af[s] = *(const bf16x8*)&H2p[((long)(mtile * 8 + s) * 64 + ln) * 8];

  f32x4 acc3[16];
  #pragma unroll
  for (int nt = 0; nt < 16; ++nt) acc3[nt] = vzero;

  Stage32 stA, stB;
  stage_load(stA, w1p, tid);
  stage_load(stB, w2p, tid);

  for (int f = 0; f < 16; ++f) {
    stage_commit(stA, bufA, tid);
    stage_commit(stB, bufB, tid);
    __syncthreads();
    if (f < 15) {
      stage_load(stA, w1p + (f + 1) * 16384, tid);
      stage_load(stB, w2p + (f + 1) * 16384, tid);
    }
    f32x4 ga[4];
    #pragma unroll
    for (int nt = 0; nt < 4; ++nt) ga[nt] = vzero;
    #pragma unroll
    for (int s = 0; s < 8; ++s) {
      #pragma unroll
      for (int nt = 0; nt < 4; ++nt) {
        bf16x8 b = *(const bf16x8*)&bufA[(nt * 8 + s) * 512 + ln * 8];
        ga[nt] = mfma16(af[s], b, ga[nt]);
      }
    }
    #pragma unroll
    for (int nt = 0; nt < 4; ++nt) {
      const int n = f * 64 + nt * 16 + lr;
      const float bias = bff1[n];
      #pragma unroll
      for (int reg = 0; reg < 4; ++reg) {
        sG[(m0 + lq * 4 + reg) * SGPAD + nt * 16 + lr] = f2bf(gelu_fast(ga[nt][reg] + bias));
      }
    }
    // wave-private sG rows: no barrier between FF1 and FF2
    #pragma unroll
    for (int s2 = 0; s2 < 2; ++s2) {
      bf16x8 ag = *(const bf16x8*)&sG[(m0 + lr) * SGPAD + s2 * 32 + lq * 8];
      #pragma unroll
      for (int nt = 0; nt < 16; ++nt) {
        bf16x8 b = *(const bf16x8*)&bufB[(s2 * 16 + nt) * 512 + ln * 8];
        acc3[nt] = mfma16(ag, b, acc3[nt]);
      }
    }
    __syncthreads();
  }
  #pragma unroll
  for (int nt = 0; nt < 16; ++nt) {
    const int col = nt * 16 + lr;
    const float bias = bff2[col];
    #pragma unroll
    for (int reg = 0; reg < 4; ++reg) {
      const int row = mtile * 16 + lq * 4 + reg;
      const long gi = (long)row * DIM + col;
      X[gi] = X[gi] + acc3[nt][reg] + bias;
    }
  }
}

// ---------------------------------------------------------------------------
// k_pool: masked mean pool + log1p(count) -> F PACKED bf16 [8192 x 320].
// 256 blocks x 32 chains (8 threads/chain).
// ---------------------------------------------------------------------------
__global__ __launch_bounds__(256) void k_pool(
    const float* __restrict__ X, const int* __restrict__ NPICK,
    const float* __restrict__ count, unsigned short* __restrict__ Fp)
{
  const int tid = threadIdx.x;
  const int cc = tid >> 3, p = tid & 7;
  const int chain = blockIdx.x * 32 + cc;
  const int np = NPICK[chain];
  const float inv = (np > 0) ? (1.f / (float)np) : 0.f;
  const int rtile = chain >> 4, lr = chain & 15;
  const float4* xb = (const float4*)(X + (long)chain * KTOK * DIM);
  #pragma unroll
  for (int i = 0; i < 8; i += 2) {
    float4 s0 = make_float4(0.f, 0.f, 0.f, 0.f);
    float4 s1 = make_float4(0.f, 0.f, 0.f, 0.f);
    for (int j = 0; j < np; ++j) {
      float4 t0 = xb[j * 64 + p * 8 + i];
      float4 t1 = xb[j * 64 + p * 8 + i + 1];
      s0.x += t0.x; s0.y += t0.y; s0.z += t0.z; s0.w += t0.w;
      s1.x += t1.x; s1.y += t1.y; s1.z += t1.z; s1.w += t1.w;
    }
    const int q = p * 4 + (i >> 1);
    const int s = q >> 2, lq = q & 3;
    u16x8 o;
    o[0] = f2bf(s0.x * inv); o[1] = f2bf(s0.y * inv);
    o[2] = f2bf(s0.z * inv); o[3] = f2bf(s0.w * inv);
    o[4] = f2bf(s1.x * inv); o[5] = f2bf(s1.y * inv);
    o[6] = f2bf(s1.z * inv); o[7] = f2bf(s1.w * inv);
    *(u16x8*)&Fp[((long)(rtile * 10 + s) * 64 + lq * 16 + lr) * 8] = o;
  }
  if (p == 7) {
    #pragma unroll
    for (int q = 32; q < 40; ++q) {
      const int s = q >> 2, lq = q & 3;
      u16x8 o = {0,0,0,0,0,0,0,0};
      if (q == 32) o[0] = f2bf(log1pf(count[chain]));
      *(u16x8*)&Fp[((long)(rtile * 10 + s) * 64 + lq * 16 + lr) * 8] = o;
    }
  }
}

// ---------------------------------------------------------------------------
// k_headmlp: out += partial over FF-quarter of gelu(F@wout1^T+b1)@wout2^T
// (+ bout2 from quarter 0). 512 thr = 8 waves = 128 chains; grid 64 m-chunks
// x 4 FF-quarters = 256 blocks.
// ---------------------------------------------------------------------------
__global__ __launch_bounds__(512, 2) void k_headmlp(
    const unsigned short* __restrict__ Fp,
    const unsigned short* __restrict__ wo1p, const unsigned short* __restrict__ wo2p,
    const float* __restrict__ bout1, const float* __restrict__ bout2,
    float* __restrict__ out)
{
  __shared__ unsigned short bufA[20480];   // 40 KB: wout1 f-chunk
  __shared__ unsigned short bufB[16384];   // 32 KB: wout2 f-chunk
  __shared__ unsigned short sG[128 * SGPAD];
  const int tid = threadIdx.x;
  const int fq = blockIdx.x & 3;
  const int mchunk = blockIdx.x >> 2;
  const int wv = tid >> 6, ln = tid & 63;
  const int lr = ln & 15, lq = ln >> 4;
  const int m0 = wv * 16;
  const int rtile = mchunk * 8 + wv;
  const f32x4 vzero = {0.f, 0.f, 0.f, 0.f};

  bf16x8 af[10];
  #pragma unroll
  for (int s = 0; s < 10; ++s)
    af[s] = *(const bf16x8*)&Fp[((long)(rtile * 10 + s) * 64 + ln) * 8];

  f32x4 oacc[16];
  #pragma unroll
  for (int nt = 0; nt < 16; ++nt) oacc[nt] = vzero;

  u16x8 rA[5]; u16x8 rB[4];
  {
    const unsigned short* a0 = wo1p + (fq * 4) * 20480;
    const unsigned short* b0 = wo2p + (fq * 4) * 16384;
    #pragma unroll
    for (int i = 0; i < 5; ++i) rA[i] = *(const u16x8*)&a0[(tid + i * 512) * 8];
    #pragma unroll
    for (int i = 0; i < 4; ++i) rB[i] = *(const u16x8*)&b0[(tid + i * 512) * 8];
  }

  for (int it = 0; it < 4; ++it) {
    const int f = fq * 4 + it;
    #pragma unroll
    for (int i = 0; i < 5; ++i) *(u16x8*)&bufA[(tid + i * 512) * 8] = rA[i];
    #pragma unroll
    for (int i = 0; i < 4; ++i) *(u16x8*)&bufB[(tid + i * 512) * 8] = rB[i];
    __syncthreads();
    if (it < 3) {
      const unsigned short* a0 = wo1p + (f + 1) * 20480;
      const unsigned short* b0 = wo2p + (f + 1) * 16384;
      #pragma unroll
      for (int i = 0; i < 5; ++i) rA[i] = *(const u16x8*)&a0[(tid + i * 512) * 8];
      #pragma unroll
      for (int i = 0; i < 4; ++i) rB[i] = *(const u16x8*)&b0[(tid + i * 512) * 8];
    }
    f32x4 ga[4];
    #pragma unroll
    for (int nt = 0; nt < 4; ++nt) ga[nt] = vzero;
    #pragma unroll
    for (int s = 0; s < 10; ++s) {
      #pragma unroll
      for (int nt = 0; nt < 4; ++nt) {
        bf16x8 b = *(const bf16x8*)&bufA[(nt * 10 + s) * 512 + ln * 8];
        ga[nt] = mfma16(af[s], b, ga[nt]);
      }
    }
    #pragma unroll
    for (int nt = 0; nt < 4; ++nt) {
      const int n = f * 64 + nt * 16 + lr;
      const float bias = bout1[n];
      #pragma unroll
      for (int reg = 0; reg < 4; ++reg) {
        sG[(m0 + lq * 4 + reg) * SGPAD + nt * 16 + lr] = f2bf(gelu_fast(ga[nt][reg] + bias));
      }
    }
    #pragma unroll
    for (int s2 = 0; s2 < 2; ++s2) {
      bf16x8 ag = *(const bf16x8*)&sG[(m0 + lr) * SGPAD + s2 * 32 + lq * 8];
      #pragma unroll
      for (int nt = 0; nt < 16; ++nt) {
        bf16x8 b = *(const bf16x8*)&bufB[(s2 * 16 + nt) * 512 + ln * 8];
        oacc[nt] = mfma16(ag, b, oacc[nt]);
      }
    }
    __syncthreads();
  }
  #pragma unroll
  for (int nt = 0; nt < 16; ++nt) {
    const int col = nt * 16 + lr;
    const float bias = (fq == 0) ? bout2[col] : 0.f;
    #pragma unroll
    for (int reg = 0; reg < 4; ++reg) {
      const int row = mchunk * 128 + m0 + lq * 4 + reg;
      atomicAdd(&out[(long)row * DIM + col], oacc[nt][reg] + bias);
    }
  }
}

// ---------------------------------------------------------------------------
extern "C" void kernel_launch(void* const* d_in, const int* in_sizes, int n_in,
                              void* d_out, int out_size, void* d_ws, size_t ws_size,
                              hipStream_t stream) {
  (void)in_sizes; (void)n_in; (void)out_size; (void)ws_size;
  const float* v          = (const float*)d_in[0];
  const int*   batch_idx  = (const int*)  d_in[1];
  const int*   mask       = (const int*)  d_in[2];
  const float* count      = (const float*)d_in[3];
  const float* rank       = (const float*)d_in[4];
  const float* pe         = (const float*)d_in[5];
  const float* w_qkv      = (const float*)d_in[6];
  const float* b_qkv      = (const float*)d_in[7];
  const float* w_o        = (const float*)d_in[8];
  const float* b_o        = (const float*)d_in[9];
  const float* ln1g       = (const float*)d_in[10];
  const float* ln1b       = (const float*)d_in[11];
  const float* ln2g       = (const float*)d_in[12];
  const float* ln2b       = (const float*)d_in[13];
  const float* w_ff1      = (const float*)d_in[14];
  const float* b_ff1      = (const float*)d_in[15];
  const float* w_ff2      = (const float*)d_in[16];
  const float* b_ff2      = (const float*)d_in[17];
  const float* w_out1     = (const float*)d_in[18];
  const float* b_out1     = (const float*)d_in[19];
  const float* w_out2     = (const float*)d_in[20];
  const float* b_out2     = (const float*)d_in[21];
  float* out = (float*)d_out;

  char* ws = (char*)d_ws;
  float*          X     = (float*)ws;                              // 67,108,864
  unsigned short* H1p   = (unsigned short*)(ws + 67108864);        // 33,554,432
  unsigned short* Op    = H1p;                                     // alias: H1p dead after k_qkv
  unsigned short* QKVp  = (unsigned short*)(ws + 100663296);       // 100,663,296 (65536x768 bf16)
  unsigned short* H2p   = QKVp;                                    // alias: QKVp dead after k_attn
  unsigned short* Fp    = (unsigned short*)(ws + 134217728);       // alias inside QKVp region
  int*            NPICK = (int*)(ws + 201326592);                  //     32,768
  unsigned short* wq_bf   = (unsigned short*)(ws + 201359360);     //    393,216
  unsigned short* wo_bf   = (unsigned short*)(ws + 201752576);     //    131,072
  unsigned short* wff1_bf = (unsigned short*)(ws + 201883648);     //    524,288
  unsigned short* wff2_bf = (unsigned short*)(ws + 202407936);     //    524,288 (k-major)
  unsigned short* wo1_bf  = (unsigned short*)(ws + 202932224);     //    655,360 (n-major, f-chunked)
  unsigned short* wo2_bf  = (unsigned short*)(ws + 203587584);     //    524,288 (k-major) -> end 204,111,872

  k_prep<<<PREP_GROUPS / 256, 256, 0, stream>>>(
      w_qkv, w_o, w_ff1, w_ff2, w_out1, w_out2,
      wq_bf, wo_bf, wff1_bf, wff2_bf, wo1_bf, wo2_bf);

  k_sel<<<8192, 256, 0, stream>>>(v, batch_idx, mask, rank, pe,
                                  ln1g, ln1b, X, H1p, NPICK);

  k_qkv<<<512, 512, 0, stream>>>(H1p, QKVp, wq_bf, b_qkv);

  k_attn<<<2048, 256, 0, stream>>>(QKVp, NPICK, Op);

  k_oproj<<<512, 512, 0, stream>>>(Op, X, wo_bf, b_o);

  k_ln2<<<1024, 256, 0, stream>>>(X, ln2g, ln2b, H2p);

  k_ff<<<512, 512, 0, stream>>>(X, H2p, wff1_bf, wff2_bf, b_ff1, b_ff2);

  k_pool<<<256, 256, 0, stream>>>(X, NPICK, count, Fp);

  hipMemsetAsync(out, 0, (size_t)8192 * 256 * sizeof(float), stream);

  k_headmlp<<<256, 512, 0, stream>>>(Fp, wo1_bf, wo2_bf, b_out1, b_out2, out);
}